// Round 15
// baseline (106.964 us; speedup 1.0000x reference)
//
#include <hip/hip_runtime.h>
#include <hip/hip_bf16.h>
#include <stdint.h>

constexpr int B_ = 2, L_ = 2048, DM = 768, NH_ = 12, F_ = 16, DH_ = 64;
constexpr int CH = 32, NCH = L_ / CH;  // scan chunking (32-row chunks)

typedef __bf16 bf16x8 __attribute__((ext_vector_type(8)));
typedef __bf16 bf16x4 __attribute__((ext_vector_type(4)));
typedef float f32x4 __attribute__((ext_vector_type(4)));
typedef float f32x16 __attribute__((ext_vector_type(16)));
typedef unsigned u32x2 __attribute__((ext_vector_type(2)));

#define GLOAD16(g, l)                                                        \
  __builtin_amdgcn_global_load_lds(                                          \
      (const __attribute__((address_space(1))) void*)(g),                    \
      (__attribute__((address_space(3))) void*)(l), 16, 0, 0)

__device__ __forceinline__ unsigned cvt_pk_bf16(float lo, float hi) {
  unsigned r;
  asm("v_cvt_pk_bf16_f32 %0, %1, %2" : "=v"(r) : "v"(lo), "v"(hi));
  return r;
}

union pa_u { unsigned u[4]; bf16x8 v; };

__device__ __forceinline__ void pack_p(const f32x16& s, pa_u& pa0, pa_u& pa1) {
  unsigned w0 = cvt_pk_bf16(s[0], s[1]),   w1 = cvt_pk_bf16(s[2], s[3]);
  unsigned w2 = cvt_pk_bf16(s[4], s[5]),   w3 = cvt_pk_bf16(s[6], s[7]);
  unsigned w4 = cvt_pk_bf16(s[8], s[9]),   w5 = cvt_pk_bf16(s[10], s[11]);
  unsigned w6 = cvt_pk_bf16(s[12], s[13]), w7 = cvt_pk_bf16(s[14], s[15]);
  u32x2 r0 = __builtin_amdgcn_permlane32_swap(w0, w2, false, false);
  u32x2 r1 = __builtin_amdgcn_permlane32_swap(w1, w3, false, false);
  u32x2 r2 = __builtin_amdgcn_permlane32_swap(w4, w6, false, false);
  u32x2 r3 = __builtin_amdgcn_permlane32_swap(w5, w7, false, false);
  pa0.u[0] = r0[0]; pa0.u[1] = r1[0]; pa0.u[2] = r0[1]; pa0.u[3] = r1[1];
  pa1.u[0] = r2[0]; pa1.u[1] = r3[0]; pa1.u[2] = r2[1]; pa1.u[3] = r3[1];
}

// ---------------- prep: LDS-tiled weight transposes + hs cast ------------
__global__ __launch_bounds__(256)
void prep_kernel(const float* __restrict__ hs, const float* __restrict__ Wq,
                 const float* __restrict__ Wk, const float* __restrict__ Wv,
                 const float* __restrict__ Wo, __bf16* __restrict__ hsb,
                 __bf16* __restrict__ WqkvT, __bf16* __restrict__ WoT) {
  int bx = blockIdx.x;
  if (bx < 1440) {
    const float* src; __bf16* dst; int C, kt, nt;
    int id = bx;
    if (id < 144)      { src = Wq; dst = WqkvT;             C = 192; kt = id / 6;  nt = id % 6;  }
    else if (id < 288) { id -= 144; src = Wk; dst = WqkvT + (size_t)192 * 768; C = 192; kt = id / 6;  nt = id % 6;  }
    else if (id < 864) { id -= 288; src = Wv; dst = WqkvT + (size_t)384 * 768; C = 768; kt = id / 24; nt = id % 24; }
    else               { id -= 864; src = Wo; dst = WoT;    C = 768; kt = id / 24; nt = id % 24; }
    __shared__ float ld[32][33];
    int tid = threadIdx.x;
    int r = tid >> 3, cg = tid & 7;
    int k0 = kt * 32, n0 = nt * 32;
    float4 v = *(const float4*)(src + (size_t)(k0 + r) * C + n0 + cg * 4);
    ld[r][cg * 4 + 0] = v.x;
    ld[r][cg * 4 + 1] = v.y;
    ld[r][cg * 4 + 2] = v.z;
    ld[r][cg * 4 + 3] = v.w;
    __syncthreads();
    int nl = tid >> 3, kg = tid & 7;
    bf16x4 o;
#pragma unroll
    for (int j = 0; j < 4; j++) o[j] = (__bf16)ld[kg * 4 + j][nl];
    *(bf16x4*)(dst + (size_t)(n0 + nl) * 768 + k0 + kg * 4) = o;
  } else {
    int base = (bx - 1440) * 2048 + threadIdx.x * 8;
    float4 a = *(const float4*)(hs + base);
    float4 b4 = *(const float4*)(hs + base + 4);
    bf16x8 o;
    o[0] = (__bf16)a.x;  o[1] = (__bf16)a.y;  o[2] = (__bf16)a.z;  o[3] = (__bf16)a.w;
    o[4] = (__bf16)b4.x; o[5] = (__bf16)b4.y; o[6] = (__bf16)b4.z; o[7] = (__bf16)b4.w;
    *(bf16x8*)(hsb + base) = o;
  }
}

// ---------------- single-wave barrier-free GEMM tile core ----------------
// One 64-thread wave computes a 64x64 tile with wave-private dbuf LDS.
// No __syncthreads anywhere: staging consumer = same wave, vmcnt(0) only.

// projection GEMM: A=hsb (4096x768), Bt=WqkvT (1152x768) -> Qh/Kh/Vh + csum
__global__ __launch_bounds__(64)
void gemm_projF(const __bf16* __restrict__ A, const __bf16* __restrict__ Bt,
                __bf16* __restrict__ Qh, __bf16* __restrict__ Kh,
                __bf16* __restrict__ Vh, float* __restrict__ csum) {
  __shared__ __align__(16) __bf16 Al[2][64 * 32];
  __shared__ __align__(16) __bf16 Bl[2][64 * 32];
  int l = threadIdx.x, lr = l & 15, lg = l >> 4;
  int n0 = blockIdx.x * 64, m0 = blockIdx.y * 64;
  const __bf16* Ab = A + (size_t)m0 * DM;
  const __bf16* Bb = Bt + (size_t)n0 * DM;
  f32x4 acc[4][4] = {};

  auto stage = [&](int buf, int k0) {
#pragma unroll
    for (int i = 0; i < 4; i++) {
      int idx = i * 64 + l;  // 256 chunks = 64 rows x 4 k-chunks
      GLOAD16(Ab + (size_t)(idx >> 2) * DM + k0 + (idx & 3) * 8, &Al[buf][idx * 8]);
    }
#pragma unroll
    for (int i = 0; i < 4; i++) {
      int idx = i * 64 + l;
      GLOAD16(Bb + (size_t)(idx >> 2) * DM + k0 + (idx & 3) * 8, &Bl[buf][idx * 8]);
    }
  };

  stage(0, 0);
  asm volatile("s_waitcnt vmcnt(0)" ::: "memory");
  int cur = 0;
  for (int t = 0; t < DM / 32; t++) {
    if (t + 1 < DM / 32) stage(cur ^ 1, (t + 1) * 32);
    bf16x8 af[4], bf[4];
#pragma unroll
    for (int mi = 0; mi < 4; mi++)
      af[mi] = *(const bf16x8*)&Al[cur][(mi * 16 + lr) * 32 + lg * 8];
#pragma unroll
    for (int ni = 0; ni < 4; ni++)
      bf[ni] = *(const bf16x8*)&Bl[cur][(ni * 16 + lr) * 32 + lg * 8];
#pragma unroll
    for (int mi = 0; mi < 4; mi++)
#pragma unroll
      for (int ni = 0; ni < 4; ni++)
        acc[mi][ni] = __builtin_amdgcn_mfma_f32_16x16x32_bf16(
            af[mi], bf[ni], acc[mi][ni], 0, 0, 0);
    asm volatile("s_waitcnt vmcnt(0)" ::: "memory");
    cur ^= 1;
  }

  // scatter to per-head bf16 buffers
#pragma unroll
  for (int mi = 0; mi < 4; mi++)
#pragma unroll
    for (int ni = 0; ni < 4; ni++) {
      int n = n0 + ni * 16 + lr;
#pragma unroll
      for (int r = 0; r < 4; r++) {
        int m = m0 + mi * 16 + lg * 4 + r;
        float v = acc[mi][ni][r];
        int b = m >> 11, ll = m & 2047;
        if (n < 192)
          Qh[((size_t)(b * NH_ + (n >> 4)) * L_ + ll) * F_ + (n & 15)] = (__bf16)v;
        else if (n < 384)
          Kh[((size_t)(b * NH_ + ((n - 192) >> 4)) * L_ + ll) * F_ + ((n - 192) & 15)] = (__bf16)v;
        else
          Vh[((size_t)(b * NH_ + ((n - 384) >> 6)) * L_ + ll) * DH_ + ((n - 384) & 63)] = (__bf16)v;
      }
    }
  // per-32-row-chunk column sums: wave covers 2 chunks (rows m0.. / +32..)
  int b = m0 >> 11;
#pragma unroll
  for (int ni = 0; ni < 4; ni++) {
#pragma unroll
    for (int pair = 0; pair < 2; pair++) {
      float cs = 0.f;
#pragma unroll
      for (int mi = 2 * pair; mi < 2 * pair + 2; mi++)
#pragma unroll
        for (int r = 0; r < 4; r++) cs += (float)(__bf16)acc[mi][ni][r];
      cs += __shfl_xor(cs, 16, 64);
      cs += __shfl_xor(cs, 32, 64);
      if (lg == 0) {
        int n = n0 + ni * 16 + lr;
        if (n >= 192) {
          int ch32 = ((m0 & 2047) >> 5) + pair;
          int h, c;
          if (n < 384) { h = (n - 192) >> 4; c = (n - 192) & 15; }
          else         { h = (n - 384) >> 6; c = 16 + ((n - 384) & 63); }
          csum[((size_t)(b * NH_ + h) * NCH + ch32) * 80 + c] = cs;
        }
      }
    }
  }
}

// output GEMM: A=Yb (4096x768), Bt=WoT (768x768) -> out fp32
__global__ __launch_bounds__(64)
void gemm2_sw(const __bf16* __restrict__ A, const __bf16* __restrict__ Bt,
              float* __restrict__ C) {
  __shared__ __align__(16) __bf16 Al[2][64 * 32];
  __shared__ __align__(16) __bf16 Bl[2][64 * 32];
  int l = threadIdx.x, lr = l & 15, lg = l >> 4;
  int n0 = blockIdx.x * 64, m0 = blockIdx.y * 64;
  const __bf16* Ab = A + (size_t)m0 * DM;
  const __bf16* Bb = Bt + (size_t)n0 * DM;
  f32x4 acc[4][4] = {};

  auto stage = [&](int buf, int k0) {
#pragma unroll
    for (int i = 0; i < 4; i++) {
      int idx = i * 64 + l;
      GLOAD16(Ab + (size_t)(idx >> 2) * DM + k0 + (idx & 3) * 8, &Al[buf][idx * 8]);
    }
#pragma unroll
    for (int i = 0; i < 4; i++) {
      int idx = i * 64 + l;
      GLOAD16(Bb + (size_t)(idx >> 2) * DM + k0 + (idx & 3) * 8, &Bl[buf][idx * 8]);
    }
  };

  stage(0, 0);
  asm volatile("s_waitcnt vmcnt(0)" ::: "memory");
  int cur = 0;
  for (int t = 0; t < DM / 32; t++) {
    if (t + 1 < DM / 32) stage(cur ^ 1, (t + 1) * 32);
    bf16x8 af[4], bf[4];
#pragma unroll
    for (int mi = 0; mi < 4; mi++)
      af[mi] = *(const bf16x8*)&Al[cur][(mi * 16 + lr) * 32 + lg * 8];
#pragma unroll
    for (int ni = 0; ni < 4; ni++)
      bf[ni] = *(const bf16x8*)&Bl[cur][(ni * 16 + lr) * 32 + lg * 8];
#pragma unroll
    for (int mi = 0; mi < 4; mi++)
#pragma unroll
      for (int ni = 0; ni < 4; ni++)
        acc[mi][ni] = __builtin_amdgcn_mfma_f32_16x16x32_bf16(
            af[mi], bf[ni], acc[mi][ni], 0, 0, 0);
    asm volatile("s_waitcnt vmcnt(0)" ::: "memory");
    cur ^= 1;
  }

#pragma unroll
  for (int mi = 0; mi < 4; mi++)
#pragma unroll
    for (int ni = 0; ni < 4; ni++) {
      int n = n0 + ni * 16 + lr;
#pragma unroll
      for (int r = 0; r < 4; r++) {
        int m = m0 + mi * 16 + lg * 4 + r;
        C[(size_t)m * DM + n] = acc[mi][ni][r];
      }
    }
}

// ---------------- apply: prefix base + in-chunk mean scan (bf16 in) ------
__global__ __launch_bounds__(128)
void scan_apply(const __bf16* __restrict__ Kh, const __bf16* __restrict__ Vh,
                const float* __restrict__ csum,
                __bf16* __restrict__ CKh, __bf16* __restrict__ CVf,
                __bf16* __restrict__ Yb) {
  int bh = blockIdx.y, ch = blockIdx.x;
  int b = bh / NH_, h = bh % NH_;
  int c = threadIdx.x;
  if (c >= 80) return;
  float run = 0.f;
  for (int j = 0; j < ch; j++) run += csum[((size_t)bh * NCH + j) * 80 + c];
  if (c < 16) {
    const __bf16* src = Kh + ((size_t)bh * L_ + ch * CH) * F_ + c;
    __bf16* ckp = CKh + ((size_t)bh * L_ + ch * CH) * F_ + c;
    for (int r = 0; r < CH; r++) {
      float val = (float)src[(size_t)r * F_];
      run += val;
      float mean = run * __builtin_amdgcn_rcpf((float)(ch * CH + r + 1));
      ckp[(size_t)r * F_] = (__bf16)(val - mean);
    }
  } else {
    int d = c - 16;
    const __bf16* src = Vh + ((size_t)bh * L_ + ch * CH) * DH_ + d;
    __bf16* cvbase = CVf + (size_t)bh * 128 * 1024;
    __bf16* yp = Yb + ((size_t)(b * L_ + ch * CH)) * DM + h * DH_ + d;
    for (int r = 0; r < CH; r++) {
      float val = (float)src[(size_t)r * DH_];
      run += val;
      int p = ch * CH + r;
      float mean = run * __builtin_amdgcn_rcpf((float)(p + 1));
      cvbase[(size_t)(p >> 4) * 1024 + d * 16 + (p & 15)] = (__bf16)(val - mean);
      yp[(size_t)r * DM] = (__bf16)mean;
    }
  }
}

// ---------------- attention: paired q-tiles (uniform work), QBLK=32 ------
__global__ __launch_bounds__(256)
void attn_mfma(const __bf16* __restrict__ Qh, const __bf16* __restrict__ CKh,
               const __bf16* __restrict__ CVf, __bf16* __restrict__ qkv,
               float* __restrict__ rs2) {
  __shared__ float slab[4][32][65];
  __shared__ float s2slab[4][32];
  int bh = blockIdx.y;
  int pairi = blockIdx.x;
  int tid = threadIdx.x;
  int w = tid >> 6, l = tid & 63;
  int lp = l & 31, hi = l >> 5;
  const __bf16* ckb = CKh + (size_t)bh * L_ * F_;
  const __bf16* cvb = CVf + (size_t)bh * 128 * 1024;

#pragma unroll
  for (int half = 0; half < 2; half++) {
    int ti = half ? (63 - pairi) : pairi;
    int q0 = ti * 32;
    bf16x8 qb = *(const bf16x8*)(Qh + ((size_t)bh * L_ + q0 + lp) * F_ + hi * 8);
    f32x16 pv0 = {}, pv1 = {};
    float s2 = 0.f;

    int pfirst = (w <= ti) ? w : 0;
    bf16x8 ka = *(const bf16x8*)(ckb + (size_t)(pfirst * 32 + lp) * F_ + hi * 8);
    const __bf16* cvp = cvb + (size_t)(2 * pfirst) * 1024 + lp * 16 + hi * 8;
    bf16x8 bv0 = *(const bf16x8*)(cvp);
    bf16x8 bv1 = *(const bf16x8*)(cvp + 512);
    bf16x8 bv2 = *(const bf16x8*)(cvp + 1024);
    bf16x8 bv3 = *(const bf16x8*)(cvp + 1536);

    for (int pt = w; pt <= ti; pt += 4) {
      int ptn = (pt + 4 <= ti) ? pt + 4 : pt;  // clamped prefetch
      bf16x8 ka_n = *(const bf16x8*)(ckb + (size_t)(ptn * 32 + lp) * F_ + hi * 8);
      const __bf16* cvpn = cvb + (size_t)(2 * ptn) * 1024 + lp * 16 + hi * 8;
      bf16x8 bn0 = *(const bf16x8*)(cvpn);
      bf16x8 bn1 = *(const bf16x8*)(cvpn + 512);
      bf16x8 bn2 = *(const bf16x8*)(cvpn + 1024);
      bf16x8 bn3 = *(const bf16x8*)(cvpn + 1536);

      f32x16 s = {};
      s = __builtin_amdgcn_mfma_f32_32x32x16_bf16(ka, qb, s, 0, 0, 0);
      if (pt == ti) {
#pragma unroll
        for (int reg = 0; reg < 16; reg++) {
          int pidx = (reg & 3) + 8 * (reg >> 2) + 4 * hi;
          if (pidx > lp) s[reg] = 0.f;
        }
      }
#pragma unroll
      for (int reg = 0; reg < 16; reg++) s2 = fmaf(s[reg], s[reg], s2);
      pa_u pa0, pa1;
      pack_p(s, pa0, pa1);
      __builtin_amdgcn_s_setprio(1);
      pv0 = __builtin_amdgcn_mfma_f32_32x32x16_bf16(pa0.v, bv0, pv0, 0, 0, 0);
      pv1 = __builtin_amdgcn_mfma_f32_32x32x16_bf16(pa0.v, bv1, pv1, 0, 0, 0);
      pv0 = __builtin_amdgcn_mfma_f32_32x32x16_bf16(pa1.v, bv2, pv0, 0, 0, 0);
      pv1 = __builtin_amdgcn_mfma_f32_32x32x16_bf16(pa1.v, bv3, pv1, 0, 0, 0);
      __builtin_amdgcn_s_setprio(0);
      ka = ka_n; bv0 = bn0; bv1 = bn1; bv2 = bn2; bv3 = bn3;
    }

    s2 += __shfl_xor(s2, 32, 64);
    if (hi == 0) s2slab[w][lp] = s2;
#pragma unroll
    for (int reg = 0; reg < 16; reg++) {
      int ql = (reg & 3) + 8 * (reg >> 2) + 4 * hi;
      slab[w][ql][lp] = pv0[reg];
      slab[w][ql][32 + lp] = pv1[reg];
    }
    __syncthreads();
    if (tid < 32) {
      float v = s2slab[0][tid] + s2slab[1][tid] + s2slab[2][tid] + s2slab[3][tid];
      rs2[(size_t)bh * L_ + q0 + tid] = v * (1.0f / 128.0f);
    }
    {
      int q = tid >> 3, seg = tid & 7;
      bf16x8 o;
#pragma unroll
      for (int j = 0; j < 8; j++) {
        int d = seg * 8 + j;
        float acc = slab[0][q][d] + slab[1][q][d] + slab[2][q][d] + slab[3][q][d];
        o[j] = (__bf16)(acc * 0.125f);
      }
      *(bf16x8*)(qkv + ((size_t)bh * L_ + q0 + q) * DH_ + seg * 8) = o;
    }
    if (half == 0) __syncthreads();  // slab reuse hazard
  }
}

// ---------------- combine (denominator scan fused): Yb += qkv/denom ------
__global__ __launch_bounds__(256)
void combine_kernel(const __bf16* __restrict__ qkv, const float* __restrict__ rs2,
                    __bf16* __restrict__ Yb) {
  int bh = blockIdx.y, lt = blockIdx.x;
  int b = bh / NH_, h = bh % NH_;
  int t = threadIdx.x;
  int l0 = lt * 256;
  __shared__ float part[256];
  __shared__ float dinv[256];
  const float* rs = rs2 + (size_t)bh * L_;
  float vals[8];
  float run = 0.f;
#pragma unroll
  for (int i = 0; i < 8; i++) { run += rs[t * 8 + i]; vals[i] = run; }
  part[t] = run;
  __syncthreads();
  for (int o = 1; o < 256; o <<= 1) {
    float add = (t >= o) ? part[t - o] : 0.f;
    __syncthreads();
    part[t] += add;
    __syncthreads();
  }
  float base = (t > 0) ? part[t - 1] : 0.f;
#pragma unroll
  for (int i = 0; i < 8; i++) {
    int ll = t * 8 + i;
    if (ll >= l0 && ll < l0 + 256)
      dinv[ll - l0] = 1.0f / ((float)(ll + 1) + base + vals[i]);
  }
  __syncthreads();
#pragma unroll
  for (int it = 0; it < 8; it++) {
    int v = it * 256 + t;
    int ll = v >> 3, d8 = v & 7;
    bf16x8 q8 = *(const bf16x8*)(qkv + ((size_t)bh * L_ + l0 + ll) * DH_ + d8 * 8);
    __bf16* yp = Yb + ((size_t)(b * L_ + l0 + ll)) * DM + h * DH_ + d8 * 8;
    bf16x8 y8 = *(const bf16x8*)yp;
    float iv = dinv[ll];
#pragma unroll
    for (int j = 0; j < 8; j++)
      y8[j] = (__bf16)((float)y8[j] + (float)q8[j] * iv);
    *(bf16x8*)yp = y8;
  }
}

extern "C" void kernel_launch(void* const* d_in, const int* in_sizes, int n_in,
                              void* d_out, int out_size, void* d_ws, size_t ws_size,
                              hipStream_t stream) {
  const float* hs = (const float*)d_in[0];
  const float* Wq = (const float*)d_in[1];
  const float* Wk = (const float*)d_in[2];
  const float* Wv = (const float*)d_in[3];
  const float* Wo = (const float*)d_in[4];
  float* out = (float*)d_out;
  char* w = (char*)d_ws;

  __bf16* hsb   = (__bf16*)(w);                      // 6,291,456
  __bf16* WqkvT = (__bf16*)(w + 6291456);            // 1,769,472
  __bf16* WoT   = (__bf16*)(w + 8060928);            // 1,179,648
  __bf16* Kh    = (__bf16*)(w + 9240576);            // 1,572,864
  __bf16* Vh    = (__bf16*)(w + 10813440);           // 6,291,456
  __bf16* qkvb  = (__bf16*)(w + 28114944);           // 6,291,456
  __bf16* Qh    = (__bf16*)(w + 34406400);           // 1,572,864
  __bf16* CKh   = (__bf16*)(w + 35979264);           // 1,572,864
  __bf16* CVfg  = (__bf16*)(w + 37552128);           // 6,291,456
  __bf16* Yb    = (__bf16*)(w + 43843584);           // 6,291,456
  float*  rs2   = (float*)(w + 50135040);            // 98,304
  float*  csum  = (float*)(w + 50331648);            // 491,520

  prep_kernel<<<2976, 256, 0, stream>>>(hs, Wq, Wk, Wv, Wo, hsb, WqkvT, WoT);
  dim3 g1(1152 / 64, 4096 / 64);
  gemm_projF<<<g1, 64, 0, stream>>>(hsb, WqkvT, Qh, Kh, Vh, csum);
  dim3 gs(NCH, B_ * NH_);
  scan_apply<<<gs, 128, 0, stream>>>(Kh, Vh, csum, CKh, CVfg, Yb);
  dim3 g3(32, 24);
  attn_mfma<<<g3, 256, 0, stream>>>(Qh, CKh, CVfg, qkvb, rs2);
  dim3 g5(8, 24);
  combine_kernel<<<g5, 256, 0, stream>>>(qkvb, rs2, Yb);
  dim3 g6(DM / 64, 4096 / 64);
  gemm2_sw<<<g6, 64, 0, stream>>>(Yb, WoT, out);
}

// Round 16
// 97.004 us; speedup vs baseline: 1.1027x; 1.1027x over previous
//
#include <hip/hip_runtime.h>
#include <hip/hip_bf16.h>
#include <stdint.h>

constexpr int B_ = 2, L_ = 2048, DM = 768, NH_ = 12, F_ = 16, DH_ = 64;
constexpr int CH = 32, NCH = L_ / CH;  // scan chunking (32-row chunks)

typedef __bf16 bf16x8 __attribute__((ext_vector_type(8)));
typedef __bf16 bf16x4 __attribute__((ext_vector_type(4)));
typedef float f32x4 __attribute__((ext_vector_type(4)));
typedef float f32x16 __attribute__((ext_vector_type(16)));
typedef unsigned u32x2 __attribute__((ext_vector_type(2)));

#define GLOAD16(g, l)                                                        \
  __builtin_amdgcn_global_load_lds(                                          \
      (const __attribute__((address_space(1))) void*)(g),                    \
      (__attribute__((address_space(3))) void*)(l), 16, 0, 0)

__device__ __forceinline__ unsigned cvt_pk_bf16(float lo, float hi) {
  unsigned r;
  asm("v_cvt_pk_bf16_f32 %0, %1, %2" : "=v"(r) : "v"(lo), "v"(hi));
  return r;
}

union pa_u { unsigned u[4]; bf16x8 v; };

__device__ __forceinline__ void pack_p(const f32x16& s, pa_u& pa0, pa_u& pa1) {
  unsigned w0 = cvt_pk_bf16(s[0], s[1]),   w1 = cvt_pk_bf16(s[2], s[3]);
  unsigned w2 = cvt_pk_bf16(s[4], s[5]),   w3 = cvt_pk_bf16(s[6], s[7]);
  unsigned w4 = cvt_pk_bf16(s[8], s[9]),   w5 = cvt_pk_bf16(s[10], s[11]);
  unsigned w6 = cvt_pk_bf16(s[12], s[13]), w7 = cvt_pk_bf16(s[14], s[15]);
  u32x2 r0 = __builtin_amdgcn_permlane32_swap(w0, w2, false, false);
  u32x2 r1 = __builtin_amdgcn_permlane32_swap(w1, w3, false, false);
  u32x2 r2 = __builtin_amdgcn_permlane32_swap(w4, w6, false, false);
  u32x2 r3 = __builtin_amdgcn_permlane32_swap(w5, w7, false, false);
  pa0.u[0] = r0[0]; pa0.u[1] = r1[0]; pa0.u[2] = r0[1]; pa0.u[3] = r1[1];
  pa1.u[0] = r2[0]; pa1.u[1] = r3[0]; pa1.u[2] = r2[1]; pa1.u[3] = r3[1];
}

// ---------------- prep: LDS-tiled weight transposes + hs cast ------------
__global__ __launch_bounds__(256)
void prep_kernel(const float* __restrict__ hs, const float* __restrict__ Wq,
                 const float* __restrict__ Wk, const float* __restrict__ Wv,
                 const float* __restrict__ Wo, __bf16* __restrict__ hsb,
                 __bf16* __restrict__ WqkvT, __bf16* __restrict__ WoT) {
  int bx = blockIdx.x;
  if (bx < 1440) {
    const float* src; __bf16* dst; int C, kt, nt;
    int id = bx;
    if (id < 144)      { src = Wq; dst = WqkvT;             C = 192; kt = id / 6;  nt = id % 6;  }
    else if (id < 288) { id -= 144; src = Wk; dst = WqkvT + (size_t)192 * 768; C = 192; kt = id / 6;  nt = id % 6;  }
    else if (id < 864) { id -= 288; src = Wv; dst = WqkvT + (size_t)384 * 768; C = 768; kt = id / 24; nt = id % 24; }
    else               { id -= 864; src = Wo; dst = WoT;    C = 768; kt = id / 24; nt = id % 24; }
    __shared__ float ld[32][33];
    int tid = threadIdx.x;
    int r = tid >> 3, cg = tid & 7;
    int k0 = kt * 32, n0 = nt * 32;
    float4 v = *(const float4*)(src + (size_t)(k0 + r) * C + n0 + cg * 4);
    ld[r][cg * 4 + 0] = v.x;
    ld[r][cg * 4 + 1] = v.y;
    ld[r][cg * 4 + 2] = v.z;
    ld[r][cg * 4 + 3] = v.w;
    __syncthreads();
    int nl = tid >> 3, kg = tid & 7;
    bf16x4 o;
#pragma unroll
    for (int j = 0; j < 4; j++) o[j] = (__bf16)ld[kg * 4 + j][nl];
    *(bf16x4*)(dst + (size_t)(n0 + nl) * 768 + k0 + kg * 4) = o;
  } else {
    int base = (bx - 1440) * 2048 + threadIdx.x * 8;
    float4 a = *(const float4*)(hs + base);
    float4 b4 = *(const float4*)(hs + base + 4);
    bf16x8 o;
    o[0] = (__bf16)a.x;  o[1] = (__bf16)a.y;  o[2] = (__bf16)a.z;  o[3] = (__bf16)a.w;
    o[4] = (__bf16)b4.x; o[5] = (__bf16)b4.y; o[6] = (__bf16)b4.z; o[7] = (__bf16)b4.w;
    *(bf16x8*)(hsb + base) = o;
  }
}

// ---------------- projection GEMM (BN=64), 3-buffer counted-vmcnt --------
// 128x64 tile, 576 blocks, 4 waves; wave w owns rows [w*32, w*32+32).
// Per stage: 3 VMEM instr/wave (2 A + 1 B). vmcnt(3) keeps next in flight.
__global__ __launch_bounds__(256)
void gemm_proj(const __bf16* __restrict__ A, const __bf16* __restrict__ Bt,
               int K, __bf16* __restrict__ Qh, __bf16* __restrict__ Kh,
               __bf16* __restrict__ Vh, float* __restrict__ csum) {
  __shared__ __align__(16) __bf16 Al[3][128 * 32];
  __shared__ __align__(16) __bf16 Bl[3][64 * 32];
  __shared__ float csl[4][64];
  int tid = threadIdx.x;
  int m0 = blockIdx.y * 128, n0 = blockIdx.x * 64;
  int w = tid >> 6, l = tid & 63, lr = l & 15, lg = l >> 4;
  int rowb = w * 32;
  f32x4 acc[2][4] = {};
  const __bf16* Ab = A + (size_t)m0 * K;
  const __bf16* Bb = Bt + (size_t)n0 * K;
  int nt = K / 32;
  auto stage = [&](int buf, int k0) {
#pragma unroll
    for (int i = 0; i < 2; i++) {
      int idx = i * 256 + tid;
      GLOAD16(Ab + (size_t)(idx >> 2) * K + k0 + (idx & 3) * 8, &Al[buf][idx * 8]);
    }
    GLOAD16(Bb + (size_t)(tid >> 2) * K + k0 + (tid & 3) * 8, &Bl[buf][tid * 8]);
  };
  stage(0, 0);
  stage(1, 32);
  for (int t = 0; t < nt; t++) {
    if (t + 1 < nt) {
      asm volatile("s_waitcnt vmcnt(3)" ::: "memory");
    } else {
      asm volatile("s_waitcnt vmcnt(0)" ::: "memory");
    }
    __syncthreads();
    if (t + 2 < nt) stage((t + 2) % 3, (t + 2) * 32);
    int cur = t % 3;
    bf16x8 af[2], bfr[4];
#pragma unroll
    for (int mi = 0; mi < 2; mi++)
      af[mi] = *(const bf16x8*)&Al[cur][(rowb + mi * 16 + lr) * 32 + lg * 8];
#pragma unroll
    for (int ni = 0; ni < 4; ni++)
      bfr[ni] = *(const bf16x8*)&Bl[cur][(ni * 16 + lr) * 32 + lg * 8];
#pragma unroll
    for (int mi = 0; mi < 2; mi++)
#pragma unroll
      for (int ni = 0; ni < 4; ni++)
        acc[mi][ni] = __builtin_amdgcn_mfma_f32_16x16x32_bf16(
            af[mi], bfr[ni], acc[mi][ni], 0, 0, 0);
  }
#pragma unroll
  for (int mi = 0; mi < 2; mi++)
#pragma unroll
    for (int ni = 0; ni < 4; ni++) {
      int n = n0 + ni * 16 + lr;
#pragma unroll
      for (int r = 0; r < 4; r++) {
        int m = m0 + rowb + mi * 16 + lg * 4 + r;
        float v = acc[mi][ni][r];
        int b = m >> 11, ll = m & 2047;
        if (n < 192)
          Qh[((size_t)(b * NH_ + (n >> 4)) * L_ + ll) * F_ + (n & 15)] = (__bf16)v;
        else if (n < 384)
          Kh[((size_t)(b * NH_ + ((n - 192) >> 4)) * L_ + ll) * F_ + ((n - 192) & 15)] = (__bf16)v;
        else
          Vh[((size_t)(b * NH_ + ((n - 384) >> 6)) * L_ + ll) * DH_ + ((n - 384) & 63)] = (__bf16)v;
      }
    }
  // per-32-row-chunk column sums (wave w = chunk w; bf16-rounded values)
#pragma unroll
  for (int ni = 0; ni < 4; ni++) {
    float cs = 0.f;
#pragma unroll
    for (int mi = 0; mi < 2; mi++)
#pragma unroll
      for (int r = 0; r < 4; r++) cs += (float)(__bf16)acc[mi][ni][r];
    cs += __shfl_xor(cs, 16, 64);
    cs += __shfl_xor(cs, 32, 64);
    if (lg == 0) csl[w][ni * 16 + lr] = cs;
  }
  __syncthreads();
  {
    int chs = tid >> 6, colg = tid & 63;
    int n = n0 + colg;
    if (n >= 192) {
      int b = m0 >> 11;
      int ch32 = ((m0 & 2047) >> 5) + chs;
      float v = csl[chs][colg];
      int h, c;
      if (n < 384) { h = (n - 192) >> 4; c = (n - 192) & 15; }
      else         { h = (n - 384) >> 6; c = 16 + ((n - 384) & 63); }
      csum[((size_t)(b * NH_ + h) * NCH + ch32) * 80 + c] = v;
    }
  }
}

// ---------------- output GEMM (BN=64), 3-buffer counted-vmcnt ------------
__global__ __launch_bounds__(256)
void gemm_out(const __bf16* __restrict__ A, const __bf16* __restrict__ Bt,
              int M, int N, int K, float* __restrict__ C) {
  __shared__ __align__(16) __bf16 Al[3][128 * 32];
  __shared__ __align__(16) __bf16 Bl[3][64 * 32];
  int tid = threadIdx.x;
  int m0 = blockIdx.y * 128, n0 = blockIdx.x * 64;
  int w = tid >> 6, l = tid & 63, lr = l & 15, lg = l >> 4;
  int rowb = w * 32;
  f32x4 acc[2][4] = {};
  const __bf16* Ab = A + (size_t)m0 * K;
  const __bf16* Bb = Bt + (size_t)n0 * K;
  int nt = K / 32;
  auto stage = [&](int buf, int k0) {
#pragma unroll
    for (int i = 0; i < 2; i++) {
      int idx = i * 256 + tid;
      GLOAD16(Ab + (size_t)(idx >> 2) * K + k0 + (idx & 3) * 8, &Al[buf][idx * 8]);
    }
    GLOAD16(Bb + (size_t)(tid >> 2) * K + k0 + (tid & 3) * 8, &Bl[buf][tid * 8]);
  };
  stage(0, 0);
  stage(1, 32);
  for (int t = 0; t < nt; t++) {
    if (t + 1 < nt) {
      asm volatile("s_waitcnt vmcnt(3)" ::: "memory");
    } else {
      asm volatile("s_waitcnt vmcnt(0)" ::: "memory");
    }
    __syncthreads();
    if (t + 2 < nt) stage((t + 2) % 3, (t + 2) * 32);
    int cur = t % 3;
    bf16x8 af[2], bfr[4];
#pragma unroll
    for (int mi = 0; mi < 2; mi++)
      af[mi] = *(const bf16x8*)&Al[cur][(rowb + mi * 16 + lr) * 32 + lg * 8];
#pragma unroll
    for (int ni = 0; ni < 4; ni++)
      bfr[ni] = *(const bf16x8*)&Bl[cur][(ni * 16 + lr) * 32 + lg * 8];
#pragma unroll
    for (int mi = 0; mi < 2; mi++)
#pragma unroll
      for (int ni = 0; ni < 4; ni++)
        acc[mi][ni] = __builtin_amdgcn_mfma_f32_16x16x32_bf16(
            af[mi], bfr[ni], acc[mi][ni], 0, 0, 0);
  }
#pragma unroll
  for (int mi = 0; mi < 2; mi++)
#pragma unroll
    for (int ni = 0; ni < 4; ni++) {
      int n = n0 + ni * 16 + lr;
#pragma unroll
      for (int r = 0; r < 4; r++) {
        int m = m0 + rowb + mi * 16 + lg * 4 + r;
        C[(size_t)m * N + n] = acc[mi][ni][r];
      }
    }
}

// ---------------- apply: prefix base + in-chunk mean scan (bf16 in) ------
__global__ __launch_bounds__(128)
void scan_apply(const __bf16* __restrict__ Kh, const __bf16* __restrict__ Vh,
                const float* __restrict__ csum,
                __bf16* __restrict__ CKh, __bf16* __restrict__ CVf,
                __bf16* __restrict__ Yb) {
  int bh = blockIdx.y, ch = blockIdx.x;
  int b = bh / NH_, h = bh % NH_;
  int c = threadIdx.x;
  if (c >= 80) return;
  float run = 0.f;
  for (int j = 0; j < ch; j++) run += csum[((size_t)bh * NCH + j) * 80 + c];
  if (c < 16) {
    const __bf16* src = Kh + ((size_t)bh * L_ + ch * CH) * F_ + c;
    __bf16* ckp = CKh + ((size_t)bh * L_ + ch * CH) * F_ + c;
    for (int r = 0; r < CH; r++) {
      float val = (float)src[(size_t)r * F_];
      run += val;
      float mean = run * __builtin_amdgcn_rcpf((float)(ch * CH + r + 1));
      ckp[(size_t)r * F_] = (__bf16)(val - mean);
    }
  } else {
    int d = c - 16;
    const __bf16* src = Vh + ((size_t)bh * L_ + ch * CH) * DH_ + d;
    __bf16* cvbase = CVf + (size_t)bh * 128 * 1024;
    __bf16* yp = Yb + ((size_t)(b * L_ + ch * CH)) * DM + h * DH_ + d;
    for (int r = 0; r < CH; r++) {
      float val = (float)src[(size_t)r * DH_];
      run += val;
      int p = ch * CH + r;
      float mean = run * __builtin_amdgcn_rcpf((float)(p + 1));
      cvbase[(size_t)(p >> 4) * 1024 + d * 16 + (p & 15)] = (__bf16)(val - mean);
      yp[(size_t)r * DM] = (__bf16)mean;
    }
  }
}

// ---------------- attention: paired q-tiles (uniform work), QBLK=32 ------
__global__ __launch_bounds__(256)
void attn_mfma(const __bf16* __restrict__ Qh, const __bf16* __restrict__ CKh,
               const __bf16* __restrict__ CVf, __bf16* __restrict__ qkv,
               float* __restrict__ rs2) {
  __shared__ float slab[4][32][65];
  __shared__ float s2slab[4][32];
  int bh = blockIdx.y;
  int pairi = blockIdx.x;
  int tid = threadIdx.x;
  int w = tid >> 6, l = tid & 63;
  int lp = l & 31, hi = l >> 5;
  const __bf16* ckb = CKh + (size_t)bh * L_ * F_;
  const __bf16* cvb = CVf + (size_t)bh * 128 * 1024;

#pragma unroll
  for (int half = 0; half < 2; half++) {
    int ti = half ? (63 - pairi) : pairi;
    int q0 = ti * 32;
    bf16x8 qb = *(const bf16x8*)(Qh + ((size_t)bh * L_ + q0 + lp) * F_ + hi * 8);
    f32x16 pv0 = {}, pv1 = {};
    float s2 = 0.f;

    int pfirst = (w <= ti) ? w : 0;
    bf16x8 ka = *(const bf16x8*)(ckb + (size_t)(pfirst * 32 + lp) * F_ + hi * 8);
    const __bf16* cvp = cvb + (size_t)(2 * pfirst) * 1024 + lp * 16 + hi * 8;
    bf16x8 bv0 = *(const bf16x8*)(cvp);
    bf16x8 bv1 = *(const bf16x8*)(cvp + 512);
    bf16x8 bv2 = *(const bf16x8*)(cvp + 1024);
    bf16x8 bv3 = *(const bf16x8*)(cvp + 1536);

    for (int pt = w; pt <= ti; pt += 4) {
      int ptn = (pt + 4 <= ti) ? pt + 4 : pt;  // clamped prefetch
      bf16x8 ka_n = *(const bf16x8*)(ckb + (size_t)(ptn * 32 + lp) * F_ + hi * 8);
      const __bf16* cvpn = cvb + (size_t)(2 * ptn) * 1024 + lp * 16 + hi * 8;
      bf16x8 bn0 = *(const bf16x8*)(cvpn);
      bf16x8 bn1 = *(const bf16x8*)(cvpn + 512);
      bf16x8 bn2 = *(const bf16x8*)(cvpn + 1024);
      bf16x8 bn3 = *(const bf16x8*)(cvpn + 1536);

      f32x16 s = {};
      s = __builtin_amdgcn_mfma_f32_32x32x16_bf16(ka, qb, s, 0, 0, 0);
      if (pt == ti) {
#pragma unroll
        for (int reg = 0; reg < 16; reg++) {
          int pidx = (reg & 3) + 8 * (reg >> 2) + 4 * hi;
          if (pidx > lp) s[reg] = 0.f;
        }
      }
#pragma unroll
      for (int reg = 0; reg < 16; reg++) s2 = fmaf(s[reg], s[reg], s2);
      pa_u pa0, pa1;
      pack_p(s, pa0, pa1);
      __builtin_amdgcn_s_setprio(1);
      pv0 = __builtin_amdgcn_mfma_f32_32x32x16_bf16(pa0.v, bv0, pv0, 0, 0, 0);
      pv1 = __builtin_amdgcn_mfma_f32_32x32x16_bf16(pa0.v, bv1, pv1, 0, 0, 0);
      pv0 = __builtin_amdgcn_mfma_f32_32x32x16_bf16(pa1.v, bv2, pv0, 0, 0, 0);
      pv1 = __builtin_amdgcn_mfma_f32_32x32x16_bf16(pa1.v, bv3, pv1, 0, 0, 0);
      __builtin_amdgcn_s_setprio(0);
      ka = ka_n; bv0 = bn0; bv1 = bn1; bv2 = bn2; bv3 = bn3;
    }

    s2 += __shfl_xor(s2, 32, 64);
    if (hi == 0) s2slab[w][lp] = s2;
#pragma unroll
    for (int reg = 0; reg < 16; reg++) {
      int ql = (reg & 3) + 8 * (reg >> 2) + 4 * hi;
      slab[w][ql][lp] = pv0[reg];
      slab[w][ql][32 + lp] = pv1[reg];
    }
    __syncthreads();
    if (tid < 32) {
      float v = s2slab[0][tid] + s2slab[1][tid] + s2slab[2][tid] + s2slab[3][tid];
      rs2[(size_t)bh * L_ + q0 + tid] = v * (1.0f / 128.0f);
    }
    {
      int q = tid >> 3, seg = tid & 7;
      bf16x8 o;
#pragma unroll
      for (int j = 0; j < 8; j++) {
        int d = seg * 8 + j;
        float acc = slab[0][q][d] + slab[1][q][d] + slab[2][q][d] + slab[3][q][d];
        o[j] = (__bf16)(acc * 0.125f);
      }
      *(bf16x8*)(qkv + ((size_t)bh * L_ + q0 + q) * DH_ + seg * 8) = o;
    }
    if (half == 0) __syncthreads();  // slab reuse hazard
  }
}

// ---------------- combine (denominator scan fused): Yb += qkv/denom ------
__global__ __launch_bounds__(256)
void combine_kernel(const __bf16* __restrict__ qkv, const float* __restrict__ rs2,
                    __bf16* __restrict__ Yb) {
  int bh = blockIdx.y, lt = blockIdx.x;
  int b = bh / NH_, h = bh % NH_;
  int t = threadIdx.x;
  int l0 = lt * 256;
  __shared__ float part[256];
  __shared__ float dinv[256];
  const float* rs = rs2 + (size_t)bh * L_;
  float vals[8];
  float run = 0.f;
#pragma unroll
  for (int i = 0; i < 8; i++) { run += rs[t * 8 + i]; vals[i] = run; }
  part[t] = run;
  __syncthreads();
  for (int o = 1; o < 256; o <<= 1) {
    float add = (t >= o) ? part[t - o] : 0.f;
    __syncthreads();
    part[t] += add;
    __syncthreads();
  }
  float base = (t > 0) ? part[t - 1] : 0.f;
#pragma unroll
  for (int i = 0; i < 8; i++) {
    int ll = t * 8 + i;
    if (ll >= l0 && ll < l0 + 256)
      dinv[ll - l0] = 1.0f / ((float)(ll + 1) + base + vals[i]);
  }
  __syncthreads();
#pragma unroll
  for (int it = 0; it < 8; it++) {
    int v = it * 256 + t;
    int ll = v >> 3, d8 = v & 7;
    bf16x8 q8 = *(const bf16x8*)(qkv + ((size_t)bh * L_ + l0 + ll) * DH_ + d8 * 8);
    __bf16* yp = Yb + ((size_t)(b * L_ + l0 + ll)) * DM + h * DH_ + d8 * 8;
    bf16x8 y8 = *(const bf16x8*)yp;
    float iv = dinv[ll];
#pragma unroll
    for (int j = 0; j < 8; j++)
      y8[j] = (__bf16)((float)y8[j] + (float)q8[j] * iv);
    *(bf16x8*)yp = y8;
  }
}

extern "C" void kernel_launch(void* const* d_in, const int* in_sizes, int n_in,
                              void* d_out, int out_size, void* d_ws, size_t ws_size,
                              hipStream_t stream) {
  const float* hs = (const float*)d_in[0];
  const float* Wq = (const float*)d_in[1];
  const float* Wk = (const float*)d_in[2];
  const float* Wv = (const float*)d_in[3];
  const float* Wo = (const float*)d_in[4];
  float* out = (float*)d_out;
  char* w = (char*)d_ws;

  __bf16* hsb   = (__bf16*)(w);                      // 6,291,456
  __bf16* WqkvT = (__bf16*)(w + 6291456);            // 1,769,472
  __bf16* WoT   = (__bf16*)(w + 8060928);            // 1,179,648
  __bf16* Kh    = (__bf16*)(w + 9240576);            // 1,572,864
  __bf16* Vh    = (__bf16*)(w + 10813440);           // 6,291,456
  __bf16* qkvb  = (__bf16*)(w + 28114944);           // 6,291,456
  __bf16* Qh    = (__bf16*)(w + 34406400);           // 1,572,864
  __bf16* CKh   = (__bf16*)(w + 35979264);           // 1,572,864
  __bf16* CVfg  = (__bf16*)(w + 37552128);           // 6,291,456
  __bf16* Yb    = (__bf16*)(w + 43843584);           // 6,291,456
  float*  rs2   = (float*)(w + 50135040);            // 98,304
  float*  csum  = (float*)(w + 50331648);            // 491,520

  prep_kernel<<<2976, 256, 0, stream>>>(hs, Wq, Wk, Wv, Wo, hsb, WqkvT, WoT);
  dim3 g1(1152 / 64, (B_ * L_) / 128);
  gemm_proj<<<g1, 256, 0, stream>>>(hsb, WqkvT, DM, Qh, Kh, Vh, csum);
  dim3 gs(NCH, B_ * NH_);
  scan_apply<<<gs, 128, 0, stream>>>(Kh, Vh, csum, CKh, CVfg, Yb);
  dim3 g3(32, 24);
  attn_mfma<<<g3, 256, 0, stream>>>(Qh, CKh, CVfg, qkvb, rs2);
  dim3 g5(8, 24);
  combine_kernel<<<g5, 256, 0, stream>>>(qkvb, rs2, Yb);
  dim3 g6(DM / 64, (B_ * L_) / 128);
  gemm_out<<<g6, 256, 0, stream>>>(Yb, WoT, B_ * L_, DM, DM, out);
}

// Round 18
// 91.116 us; speedup vs baseline: 1.1739x; 1.0646x over previous
//
#include <hip/hip_runtime.h>
#include <hip/hip_bf16.h>
#include <stdint.h>

constexpr int B_ = 2, L_ = 2048, DM = 768, NH_ = 12, F_ = 16, DH_ = 64;
constexpr int CH = 32, NCH = L_ / CH;  // scan chunking (32-row chunks)

typedef __bf16 bf16x8 __attribute__((ext_vector_type(8)));
typedef __bf16 bf16x4 __attribute__((ext_vector_type(4)));
typedef float f32x4 __attribute__((ext_vector_type(4)));
typedef float f32x16 __attribute__((ext_vector_type(16)));
typedef unsigned u32x2 __attribute__((ext_vector_type(2)));

#define GLOAD16(g, l)                                                        \
  __builtin_amdgcn_global_load_lds(                                          \
      (const __attribute__((address_space(1))) void*)(g),                    \
      (__attribute__((address_space(3))) void*)(l), 16, 0, 0)

__device__ __forceinline__ unsigned cvt_pk_bf16(float lo, float hi) {
  unsigned r;
  asm("v_cvt_pk_bf16_f32 %0, %1, %2" : "=v"(r) : "v"(lo), "v"(hi));
  return r;
}

// XCD-aware work remap (T1): hw-consecutive blocks round-robin XCDs; this
// gives each XCD a contiguous chunk of work ids. Requires nwg % 8 == 0.
__device__ __forceinline__ int xcd_swizzle(int flat, int nwg) {
  int cpx = nwg >> 3;
  return (flat & 7) * cpx + (flat >> 3);
}

union pa_u { unsigned u[4]; bf16x8 v; };

__device__ __forceinline__ void pack_p(const f32x16& s, pa_u& pa0, pa_u& pa1) {
  unsigned w0 = cvt_pk_bf16(s[0], s[1]),   w1 = cvt_pk_bf16(s[2], s[3]);
  unsigned w2 = cvt_pk_bf16(s[4], s[5]),   w3 = cvt_pk_bf16(s[6], s[7]);
  unsigned w4 = cvt_pk_bf16(s[8], s[9]),   w5 = cvt_pk_bf16(s[10], s[11]);
  unsigned w6 = cvt_pk_bf16(s[12], s[13]), w7 = cvt_pk_bf16(s[14], s[15]);
  u32x2 r0 = __builtin_amdgcn_permlane32_swap(w0, w2, false, false);
  u32x2 r1 = __builtin_amdgcn_permlane32_swap(w1, w3, false, false);
  u32x2 r2 = __builtin_amdgcn_permlane32_swap(w4, w6, false, false);
  u32x2 r3 = __builtin_amdgcn_permlane32_swap(w5, w7, false, false);
  pa0.u[0] = r0[0]; pa0.u[1] = r1[0]; pa0.u[2] = r0[1]; pa0.u[3] = r1[1];
  pa1.u[0] = r2[0]; pa1.u[1] = r3[0]; pa1.u[2] = r2[1]; pa1.u[3] = r3[1];
}

// ---------------- prep: LDS-tiled weight transposes + hs cast ------------
__global__ __launch_bounds__(256)
void prep_kernel(const float* __restrict__ hs, const float* __restrict__ Wq,
                 const float* __restrict__ Wk, const float* __restrict__ Wv,
                 const float* __restrict__ Wo, __bf16* __restrict__ hsb,
                 __bf16* __restrict__ WqkvT, __bf16* __restrict__ WoT) {
  int bx = blockIdx.x;
  if (bx < 1440) {
    const float* src; __bf16* dst; int C, kt, nt;
    int id = bx;
    if (id < 144)      { src = Wq; dst = WqkvT;             C = 192; kt = id / 6;  nt = id % 6;  }
    else if (id < 288) { id -= 144; src = Wk; dst = WqkvT + (size_t)192 * 768; C = 192; kt = id / 6;  nt = id % 6;  }
    else if (id < 864) { id -= 288; src = Wv; dst = WqkvT + (size_t)384 * 768; C = 768; kt = id / 24; nt = id % 24; }
    else               { id -= 864; src = Wo; dst = WoT;    C = 768; kt = id / 24; nt = id % 24; }
    __shared__ float ld[32][33];
    int tid = threadIdx.x;
    int r = tid >> 3, cg = tid & 7;
    int k0 = kt * 32, n0 = nt * 32;
    float4 v = *(const float4*)(src + (size_t)(k0 + r) * C + n0 + cg * 4);
    ld[r][cg * 4 + 0] = v.x;
    ld[r][cg * 4 + 1] = v.y;
    ld[r][cg * 4 + 2] = v.z;
    ld[r][cg * 4 + 3] = v.w;
    __syncthreads();
    int nl = tid >> 3, kg = tid & 7;
    bf16x4 o;
#pragma unroll
    for (int j = 0; j < 4; j++) o[j] = (__bf16)ld[kg * 4 + j][nl];
    *(bf16x4*)(dst + (size_t)(n0 + nl) * 768 + k0 + kg * 4) = o;
  } else {
    int base = (bx - 1440) * 2048 + threadIdx.x * 8;
    float4 a = *(const float4*)(hs + base);
    float4 b4 = *(const float4*)(hs + base + 4);
    bf16x8 o;
    o[0] = (__bf16)a.x;  o[1] = (__bf16)a.y;  o[2] = (__bf16)a.z;  o[3] = (__bf16)a.w;
    o[4] = (__bf16)b4.x; o[5] = (__bf16)b4.y; o[6] = (__bf16)b4.z; o[7] = (__bf16)b4.w;
    *(bf16x8*)(hsb + base) = o;
  }
}

// ---------------- projection GEMM (BN=64), 2-buffer, XCD-swizzled --------
// 128x64 tile, 576 blocks, 4 waves; wave w owns rows [w*32, w*32+32).
__global__ __launch_bounds__(256)
void gemm_proj(const __bf16* __restrict__ A, const __bf16* __restrict__ Bt,
               int K, __bf16* __restrict__ Qh, __bf16* __restrict__ Kh,
               __bf16* __restrict__ Vh, float* __restrict__ csum) {
  __shared__ __align__(16) __bf16 Al[2][128 * 32];
  __shared__ __align__(16) __bf16 Bl[2][64 * 32];
  __shared__ float csl[4][64];
  int tid = threadIdx.x;
  int flat = blockIdx.x + gridDim.x * blockIdx.y;
  int swz = xcd_swizzle(flat, gridDim.x * gridDim.y);
  int m0 = (swz / gridDim.x) * 128, n0 = (swz % gridDim.x) * 64;
  int w = tid >> 6, l = tid & 63, lr = l & 15, lg = l >> 4;
  int rowb = w * 32;
  f32x4 acc[2][4] = {};
  const __bf16* Ab = A + (size_t)m0 * K;
  const __bf16* Bb = Bt + (size_t)n0 * K;
  int nt = K / 32;
  auto stage = [&](int buf, int k0) {
#pragma unroll
    for (int i = 0; i < 2; i++) {
      int idx = i * 256 + tid;
      GLOAD16(Ab + (size_t)(idx >> 2) * K + k0 + (idx & 3) * 8, &Al[buf][idx * 8]);
    }
    GLOAD16(Bb + (size_t)(tid >> 2) * K + k0 + (tid & 3) * 8, &Bl[buf][tid * 8]);
  };
  stage(0, 0);
  asm volatile("s_waitcnt vmcnt(0)" ::: "memory");
  __syncthreads();
  int cur = 0;
  for (int t = 0; t < nt; t++) {
    if (t + 1 < nt) stage(cur ^ 1, (t + 1) * 32);
    bf16x8 af[2], bfr[4];
#pragma unroll
    for (int mi = 0; mi < 2; mi++)
      af[mi] = *(const bf16x8*)&Al[cur][(rowb + mi * 16 + lr) * 32 + lg * 8];
#pragma unroll
    for (int ni = 0; ni < 4; ni++)
      bfr[ni] = *(const bf16x8*)&Bl[cur][(ni * 16 + lr) * 32 + lg * 8];
#pragma unroll
    for (int mi = 0; mi < 2; mi++)
#pragma unroll
      for (int ni = 0; ni < 4; ni++)
        acc[mi][ni] = __builtin_amdgcn_mfma_f32_16x16x32_bf16(
            af[mi], bfr[ni], acc[mi][ni], 0, 0, 0);
    asm volatile("s_waitcnt vmcnt(0)" ::: "memory");
    __syncthreads();
    cur ^= 1;
  }
#pragma unroll
  for (int mi = 0; mi < 2; mi++)
#pragma unroll
    for (int ni = 0; ni < 4; ni++) {
      int n = n0 + ni * 16 + lr;
#pragma unroll
      for (int r = 0; r < 4; r++) {
        int m = m0 + rowb + mi * 16 + lg * 4 + r;
        float v = acc[mi][ni][r];
        int b = m >> 11, ll = m & 2047;
        if (n < 192)
          Qh[((size_t)(b * NH_ + (n >> 4)) * L_ + ll) * F_ + (n & 15)] = (__bf16)v;
        else if (n < 384)
          Kh[((size_t)(b * NH_ + ((n - 192) >> 4)) * L_ + ll) * F_ + ((n - 192) & 15)] = (__bf16)v;
        else
          Vh[((size_t)(b * NH_ + ((n - 384) >> 6)) * L_ + ll) * DH_ + ((n - 384) & 63)] = (__bf16)v;
      }
    }
  // per-32-row-chunk column sums (wave w = chunk w; bf16-rounded values)
#pragma unroll
  for (int ni = 0; ni < 4; ni++) {
    float cs = 0.f;
#pragma unroll
    for (int mi = 0; mi < 2; mi++)
#pragma unroll
      for (int r = 0; r < 4; r++) cs += (float)(__bf16)acc[mi][ni][r];
    cs += __shfl_xor(cs, 16, 64);
    cs += __shfl_xor(cs, 32, 64);
    if (lg == 0) csl[w][ni * 16 + lr] = cs;
  }
  __syncthreads();
  {
    int chs = tid >> 6, colg = tid & 63;
    int n = n0 + colg;
    if (n >= 192) {
      int b = m0 >> 11;
      int ch32 = ((m0 & 2047) >> 5) + chs;
      float v = csl[chs][colg];
      int h, c;
      if (n < 384) { h = (n - 192) >> 4; c = (n - 192) & 15; }
      else         { h = (n - 384) >> 6; c = 16 + ((n - 384) & 63); }
      csum[((size_t)(b * NH_ + h) * NCH + ch32) * 80 + c] = v;
    }
  }
}

// ---------------- output GEMM (BN=64), 2-buffer, XCD-swizzled ------------
__global__ __launch_bounds__(256)
void gemm_out(const __bf16* __restrict__ A, const __bf16* __restrict__ Bt,
              int M, int N, int K, float* __restrict__ C) {
  __shared__ __align__(16) __bf16 Al[2][128 * 32];
  __shared__ __align__(16) __bf16 Bl[2][64 * 32];
  int tid = threadIdx.x;
  int flat = blockIdx.x + gridDim.x * blockIdx.y;
  int swz = xcd_swizzle(flat, gridDim.x * gridDim.y);
  int m0 = (swz / gridDim.x) * 128, n0 = (swz % gridDim.x) * 64;
  int w = tid >> 6, l = tid & 63, lr = l & 15, lg = l >> 4;
  int rowb = w * 32;
  f32x4 acc[2][4] = {};
  const __bf16* Ab = A + (size_t)m0 * K;
  const __bf16* Bb = Bt + (size_t)n0 * K;
  int nt = K / 32;
  auto stage = [&](int buf, int k0) {
#pragma unroll
    for (int i = 0; i < 2; i++) {
      int idx = i * 256 + tid;
      GLOAD16(Ab + (size_t)(idx >> 2) * K + k0 + (idx & 3) * 8, &Al[buf][idx * 8]);
    }
    GLOAD16(Bb + (size_t)(tid >> 2) * K + k0 + (tid & 3) * 8, &Bl[buf][tid * 8]);
  };
  stage(0, 0);
  asm volatile("s_waitcnt vmcnt(0)" ::: "memory");
  __syncthreads();
  int cur = 0;
  for (int t = 0; t < nt; t++) {
    if (t + 1 < nt) stage(cur ^ 1, (t + 1) * 32);
    bf16x8 af[2], bfr[4];
#pragma unroll
    for (int mi = 0; mi < 2; mi++)
      af[mi] = *(const bf16x8*)&Al[cur][(rowb + mi * 16 + lr) * 32 + lg * 8];
#pragma unroll
    for (int ni = 0; ni < 4; ni++)
      bfr[ni] = *(const bf16x8*)&Bl[cur][(ni * 16 + lr) * 32 + lg * 8];
#pragma unroll
    for (int mi = 0; mi < 2; mi++)
#pragma unroll
      for (int ni = 0; ni < 4; ni++)
        acc[mi][ni] = __builtin_amdgcn_mfma_f32_16x16x32_bf16(
            af[mi], bfr[ni], acc[mi][ni], 0, 0, 0);
    asm volatile("s_waitcnt vmcnt(0)" ::: "memory");
    __syncthreads();
    cur ^= 1;
  }
#pragma unroll
  for (int mi = 0; mi < 2; mi++)
#pragma unroll
    for (int ni = 0; ni < 4; ni++) {
      int n = n0 + ni * 16 + lr;
#pragma unroll
      for (int r = 0; r < 4; r++) {
        int m = m0 + rowb + mi * 16 + lg * 4 + r;
        C[(size_t)m * N + n] = acc[mi][ni][r];
      }
    }
}

// ---------------- apply: prefix base + in-chunk mean scan (bf16 in) ------
__global__ __launch_bounds__(128)
void scan_apply(const __bf16* __restrict__ Kh, const __bf16* __restrict__ Vh,
                const float* __restrict__ csum,
                __bf16* __restrict__ CKh, __bf16* __restrict__ CVf,
                __bf16* __restrict__ Yb) {
  int bh = blockIdx.y, ch = blockIdx.x;
  int b = bh / NH_, h = bh % NH_;
  int c = threadIdx.x;
  if (c >= 80) return;
  float run = 0.f;
  for (int j = 0; j < ch; j++) run += csum[((size_t)bh * NCH + j) * 80 + c];
  if (c < 16) {
    const __bf16* src = Kh + ((size_t)bh * L_ + ch * CH) * F_ + c;
    __bf16* ckp = CKh + ((size_t)bh * L_ + ch * CH) * F_ + c;
    for (int r = 0; r < CH; r++) {
      float val = (float)src[(size_t)r * F_];
      run += val;
      float mean = run * __builtin_amdgcn_rcpf((float)(ch * CH + r + 1));
      ckp[(size_t)r * F_] = (__bf16)(val - mean);
    }
  } else {
    int d = c - 16;
    const __bf16* src = Vh + ((size_t)bh * L_ + ch * CH) * DH_ + d;
    __bf16* cvbase = CVf + (size_t)bh * 128 * 1024;
    __bf16* yp = Yb + ((size_t)(b * L_ + ch * CH)) * DM + h * DH_ + d;
    for (int r = 0; r < CH; r++) {
      float val = (float)src[(size_t)r * DH_];
      run += val;
      int p = ch * CH + r;
      float mean = run * __builtin_amdgcn_rcpf((float)(p + 1));
      cvbase[(size_t)(p >> 4) * 1024 + d * 16 + (p & 15)] = (__bf16)(val - mean);
      yp[(size_t)r * DM] = (__bf16)mean;
    }
  }
}

// ---------------- attention: paired q-tiles, QBLK=32, XCD-swizzled -------
__global__ __launch_bounds__(256)
void attn_mfma(const __bf16* __restrict__ Qh, const __bf16* __restrict__ CKh,
               const __bf16* __restrict__ CVf, __bf16* __restrict__ qkv,
               float* __restrict__ rs2) {
  __shared__ float slab[4][32][65];
  __shared__ float s2slab[4][32];
  int flat = blockIdx.x + 32 * blockIdx.y;
  int swz = xcd_swizzle(flat, 32 * 24);
  int pairi = swz & 31;
  int bh = swz >> 5;
  int tid = threadIdx.x;
  int w = tid >> 6, l = tid & 63;
  int lp = l & 31, hi = l >> 5;
  const __bf16* ckb = CKh + (size_t)bh * L_ * F_;
  const __bf16* cvb = CVf + (size_t)bh * 128 * 1024;

#pragma unroll
  for (int half = 0; half < 2; half++) {
    int ti = half ? (63 - pairi) : pairi;
    int q0 = ti * 32;
    bf16x8 qb = *(const bf16x8*)(Qh + ((size_t)bh * L_ + q0 + lp) * F_ + hi * 8);
    f32x16 pv0 = {}, pv1 = {};
    float s2 = 0.f;

    int pfirst = (w <= ti) ? w : 0;
    bf16x8 ka = *(const bf16x8*)(ckb + (size_t)(pfirst * 32 + lp) * F_ + hi * 8);
    const __bf16* cvp = cvb + (size_t)(2 * pfirst) * 1024 + lp * 16 + hi * 8;
    bf16x8 bv0 = *(const bf16x8*)(cvp);
    bf16x8 bv1 = *(const bf16x8*)(cvp + 512);
    bf16x8 bv2 = *(const bf16x8*)(cvp + 1024);
    bf16x8 bv3 = *(const bf16x8*)(cvp + 1536);

    for (int pt = w; pt <= ti; pt += 4) {
      int ptn = (pt + 4 <= ti) ? pt + 4 : pt;  // clamped prefetch
      bf16x8 ka_n = *(const bf16x8*)(ckb + (size_t)(ptn * 32 + lp) * F_ + hi * 8);
      const __bf16* cvpn = cvb + (size_t)(2 * ptn) * 1024 + lp * 16 + hi * 8;
      bf16x8 bn0 = *(const bf16x8*)(cvpn);
      bf16x8 bn1 = *(const bf16x8*)(cvpn + 512);
      bf16x8 bn2 = *(const bf16x8*)(cvpn + 1024);
      bf16x8 bn3 = *(const bf16x8*)(cvpn + 1536);

      f32x16 s = {};
      s = __builtin_amdgcn_mfma_f32_32x32x16_bf16(ka, qb, s, 0, 0, 0);
      if (pt == ti) {
#pragma unroll
        for (int reg = 0; reg < 16; reg++) {
          int pidx = (reg & 3) + 8 * (reg >> 2) + 4 * hi;
          if (pidx > lp) s[reg] = 0.f;
        }
      }
#pragma unroll
      for (int reg = 0; reg < 16; reg++) s2 = fmaf(s[reg], s[reg], s2);
      pa_u pa0, pa1;
      pack_p(s, pa0, pa1);
      __builtin_amdgcn_s_setprio(1);
      pv0 = __builtin_amdgcn_mfma_f32_32x32x16_bf16(pa0.v, bv0, pv0, 0, 0, 0);
      pv1 = __builtin_amdgcn_mfma_f32_32x32x16_bf16(pa0.v, bv1, pv1, 0, 0, 0);
      pv0 = __builtin_amdgcn_mfma_f32_32x32x16_bf16(pa1.v, bv2, pv0, 0, 0, 0);
      pv1 = __builtin_amdgcn_mfma_f32_32x32x16_bf16(pa1.v, bv3, pv1, 0, 0, 0);
      __builtin_amdgcn_s_setprio(0);
      ka = ka_n; bv0 = bn0; bv1 = bn1; bv2 = bn2; bv3 = bn3;
    }

    s2 += __shfl_xor(s2, 32, 64);
    if (hi == 0) s2slab[w][lp] = s2;
#pragma unroll
    for (int reg = 0; reg < 16; reg++) {
      int ql = (reg & 3) + 8 * (reg >> 2) + 4 * hi;
      slab[w][ql][lp] = pv0[reg];
      slab[w][ql][32 + lp] = pv1[reg];
    }
    __syncthreads();
    if (tid < 32) {
      float v = s2slab[0][tid] + s2slab[1][tid] + s2slab[2][tid] + s2slab[3][tid];
      rs2[(size_t)bh * L_ + q0 + tid] = v * (1.0f / 128.0f);
    }
    {
      int q = tid >> 3, seg = tid & 7;
      bf16x8 o;
#pragma unroll
      for (int j = 0; j < 8; j++) {
        int d = seg * 8 + j;
        float acc = slab[0][q][d] + slab[1][q][d] + slab[2][q][d] + slab[3][q][d];
        o[j] = (__bf16)(acc * 0.125f);
      }
      *(bf16x8*)(qkv + ((size_t)bh * L_ + q0 + q) * DH_ + seg * 8) = o;
    }
    if (half == 0) __syncthreads();  // slab reuse hazard
  }
}

// ---------------- combine (denominator scan fused): Yb += qkv/denom ------
__global__ __launch_bounds__(256)
void combine_kernel(const __bf16* __restrict__ qkv, const float* __restrict__ rs2,
                    __bf16* __restrict__ Yb) {
  int bh = blockIdx.y, lt = blockIdx.x;
  int b = bh / NH_, h = bh % NH_;
  int t = threadIdx.x;
  int l0 = lt * 256;
  __shared__ float part[256];
  __shared__ float dinv[256];
  const float* rs = rs2 + (size_t)bh * L_;
  float vals[8];
  float run = 0.f;
#pragma unroll
  for (int i = 0; i < 8; i++) { run += rs[t * 8 + i]; vals[i] = run; }
  part[t] = run;
  __syncthreads();
  for (int o = 1; o < 256; o <<= 1) {
    float add = (t >= o) ? part[t - o] : 0.f;
    __syncthreads();
    part[t] += add;
    __syncthreads();
  }
  float base = (t > 0) ? part[t - 1] : 0.f;
#pragma unroll
  for (int i = 0; i < 8; i++) {
    int ll = t * 8 + i;
    if (ll >= l0 && ll < l0 + 256)
      dinv[ll - l0] = 1.0f / ((float)(ll + 1) + base + vals[i]);
  }
  __syncthreads();
#pragma unroll
  for (int it = 0; it < 8; it++) {
    int v = it * 256 + t;
    int ll = v >> 3, d8 = v & 7;
    bf16x8 q8 = *(const bf16x8*)(qkv + ((size_t)bh * L_ + l0 + ll) * DH_ + d8 * 8);
    __bf16* yp = Yb + ((size_t)(b * L_ + l0 + ll)) * DM + h * DH_ + d8 * 8;
    bf16x8 y8 = *(const bf16x8*)yp;
    float iv = dinv[ll];
#pragma unroll
    for (int j = 0; j < 8; j++)
      y8[j] = (__bf16)((float)y8[j] + (float)q8[j] * iv);
    *(bf16x8*)yp = y8;
  }
}

extern "C" void kernel_launch(void* const* d_in, const int* in_sizes, int n_in,
                              void* d_out, int out_size, void* d_ws, size_t ws_size,
                              hipStream_t stream) {
  const float* hs = (const float*)d_in[0];
  const float* Wq = (const float*)d_in[1];
  const float* Wk = (const float*)d_in[2];
  const float* Wv = (const float*)d_in[3];
  const float* Wo = (const float*)d_in[4];
  float* out = (float*)d_out;
  char* w = (char*)d_ws;

  __bf16* hsb   = (__bf16*)(w);                      // 6,291,456
  __bf16* WqkvT = (__bf16*)(w + 6291456);            // 1,769,472
  __bf16* WoT   = (__bf16*)(w + 8060928);            // 1,179,648
  __bf16* Kh    = (__bf16*)(w + 9240576);            // 1,572,864
  __bf16* Vh    = (__bf16*)(w + 10813440);           // 6,291,456
  __bf16* qkvb  = (__bf16*)(w + 28114944);           // 6,291,456
  __bf16* Qh    = (__bf16*)(w + 34406400);           // 1,572,864
  __bf16* CKh   = (__bf16*)(w + 35979264);           // 1,572,864
  __bf16* CVfg  = (__bf16*)(w + 37552128);           // 6,291,456
  __bf16* Yb    = (__bf16*)(w + 43843584);           // 6,291,456
  float*  rs2   = (float*)(w + 50135040);            // 98,304
  float*  csum  = (float*)(w + 50331648);            // 491,520

  prep_kernel<<<2976, 256, 0, stream>>>(hs, Wq, Wk, Wv, Wo, hsb, WqkvT, WoT);
  dim3 g1(1152 / 64, (B_ * L_) / 128);
  gemm_proj<<<g1, 256, 0, stream>>>(hsb, WqkvT, DM, Qh, Kh, Vh, csum);
  dim3 gs(NCH, B_ * NH_);
  scan_apply<<<gs, 128, 0, stream>>>(Kh, Vh, csum, CKh, CVfg, Yb);
  dim3 g3(32, 24);
  attn_mfma<<<g3, 256, 0, stream>>>(Qh, CKh, CVfg, qkvb, rs2);
  dim3 g5(8, 24);
  combine_kernel<<<g5, 256, 0, stream>>>(qkvb, rs2, Yb);
  dim3 g6(DM / 64, (B_ * L_) / 128);
  gemm_out<<<g6, 256, 0, stream>>>(Yb, WoT, B_ * L_, DM, DM, out);
}

// Round 19
// 88.983 us; speedup vs baseline: 1.2021x; 1.0240x over previous
//
#include <hip/hip_runtime.h>
#include <hip/hip_bf16.h>
#include <stdint.h>

constexpr int B_ = 2, L_ = 2048, DM = 768, NH_ = 12, F_ = 16, DH_ = 64;
constexpr int CH = 32, NCH = L_ / CH;  // scan chunking (32-row chunks)

typedef __bf16 bf16x8 __attribute__((ext_vector_type(8)));
typedef __bf16 bf16x4 __attribute__((ext_vector_type(4)));
typedef float f32x4 __attribute__((ext_vector_type(4)));
typedef float f32x16 __attribute__((ext_vector_type(16)));
typedef unsigned u32x2 __attribute__((ext_vector_type(2)));

#define GLOAD16(g, l)                                                        \
  __builtin_amdgcn_global_load_lds(                                          \
      (const __attribute__((address_space(1))) void*)(g),                    \
      (__attribute__((address_space(3))) void*)(l), 16, 0, 0)

__device__ __forceinline__ unsigned cvt_pk_bf16(float lo, float hi) {
  unsigned r;
  asm("v_cvt_pk_bf16_f32 %0, %1, %2" : "=v"(r) : "v"(lo), "v"(hi));
  return r;
}

// XCD-aware work remap (T1): hw-consecutive blocks round-robin XCDs; this
// gives each XCD a contiguous chunk of work ids. Requires nwg % 8 == 0.
__device__ __forceinline__ int xcd_swizzle(int flat, int nwg) {
  int cpx = nwg >> 3;
  return (flat & 7) * cpx + (flat >> 3);
}

union pa_u { unsigned u[4]; bf16x8 v; };

__device__ __forceinline__ void pack_p(const f32x16& s, pa_u& pa0, pa_u& pa1) {
  unsigned w0 = cvt_pk_bf16(s[0], s[1]),   w1 = cvt_pk_bf16(s[2], s[3]);
  unsigned w2 = cvt_pk_bf16(s[4], s[5]),   w3 = cvt_pk_bf16(s[6], s[7]);
  unsigned w4 = cvt_pk_bf16(s[8], s[9]),   w5 = cvt_pk_bf16(s[10], s[11]);
  unsigned w6 = cvt_pk_bf16(s[12], s[13]), w7 = cvt_pk_bf16(s[14], s[15]);
  u32x2 r0 = __builtin_amdgcn_permlane32_swap(w0, w2, false, false);
  u32x2 r1 = __builtin_amdgcn_permlane32_swap(w1, w3, false, false);
  u32x2 r2 = __builtin_amdgcn_permlane32_swap(w4, w6, false, false);
  u32x2 r3 = __builtin_amdgcn_permlane32_swap(w5, w7, false, false);
  pa0.u[0] = r0[0]; pa0.u[1] = r1[0]; pa0.u[2] = r0[1]; pa0.u[3] = r1[1];
  pa1.u[0] = r2[0]; pa1.u[1] = r3[0]; pa1.u[2] = r2[1]; pa1.u[3] = r3[1];
}

// ---------------- prep: LDS-tiled weight transposes + hs cast ------------
__global__ __launch_bounds__(256)
void prep_kernel(const float* __restrict__ hs, const float* __restrict__ Wq,
                 const float* __restrict__ Wk, const float* __restrict__ Wv,
                 const float* __restrict__ Wo, __bf16* __restrict__ hsb,
                 __bf16* __restrict__ WqkvT, __bf16* __restrict__ WoT) {
  int bx = blockIdx.x;
  if (bx < 1440) {
    const float* src; __bf16* dst; int C, kt, nt;
    int id = bx;
    if (id < 144)      { src = Wq; dst = WqkvT;             C = 192; kt = id / 6;  nt = id % 6;  }
    else if (id < 288) { id -= 144; src = Wk; dst = WqkvT + (size_t)192 * 768; C = 192; kt = id / 6;  nt = id % 6;  }
    else if (id < 864) { id -= 288; src = Wv; dst = WqkvT + (size_t)384 * 768; C = 768; kt = id / 24; nt = id % 24; }
    else               { id -= 864; src = Wo; dst = WoT;    C = 768; kt = id / 24; nt = id % 24; }
    __shared__ float ld[32][33];
    int tid = threadIdx.x;
    int r = tid >> 3, cg = tid & 7;
    int k0 = kt * 32, n0 = nt * 32;
    float4 v = *(const float4*)(src + (size_t)(k0 + r) * C + n0 + cg * 4);
    ld[r][cg * 4 + 0] = v.x;
    ld[r][cg * 4 + 1] = v.y;
    ld[r][cg * 4 + 2] = v.z;
    ld[r][cg * 4 + 3] = v.w;
    __syncthreads();
    int nl = tid >> 3, kg = tid & 7;
    bf16x4 o;
#pragma unroll
    for (int j = 0; j < 4; j++) o[j] = (__bf16)ld[kg * 4 + j][nl];
    *(bf16x4*)(dst + (size_t)(n0 + nl) * 768 + k0 + kg * 4) = o;
  } else {
    int base = (bx - 1440) * 2048 + threadIdx.x * 8;
    float4 a = *(const float4*)(hs + base);
    float4 b4 = *(const float4*)(hs + base + 4);
    bf16x8 o;
    o[0] = (__bf16)a.x;  o[1] = (__bf16)a.y;  o[2] = (__bf16)a.z;  o[3] = (__bf16)a.w;
    o[4] = (__bf16)b4.x; o[5] = (__bf16)b4.y; o[6] = (__bf16)b4.z; o[7] = (__bf16)b4.w;
    *(bf16x8*)(hsb + base) = o;
  }
}

// ---------------- projection GEMM (BN=64, BK=64), 2-buffer, swizzled -----
// 128x64 tile, 576 blocks, 4 waves; wave w owns rows [w*32, w*32+32).
// BK=64 split into two [rows][32] k-half sub-tiles (conflict-free layout,
// linear gload_lds dests); 12 barrier-drains per block instead of 24.
__global__ __launch_bounds__(256)
void gemm_proj(const __bf16* __restrict__ A, const __bf16* __restrict__ Bt,
               int K, __bf16* __restrict__ Qh, __bf16* __restrict__ Kh,
               __bf16* __restrict__ Vh, float* __restrict__ csum) {
  __shared__ __align__(16) __bf16 Al[2][2][128 * 32];
  __shared__ __align__(16) __bf16 Bl[2][2][64 * 32];
  __shared__ float csl[4][64];
  int tid = threadIdx.x;
  int flat = blockIdx.x + gridDim.x * blockIdx.y;
  int swz = xcd_swizzle(flat, gridDim.x * gridDim.y);
  int m0 = (swz / gridDim.x) * 128, n0 = (swz % gridDim.x) * 64;
  int w = tid >> 6, l = tid & 63, lr = l & 15, lg = l >> 4;
  int rowb = w * 32;
  f32x4 acc[2][4] = {};
  const __bf16* Ab = A + (size_t)m0 * K;
  const __bf16* Bb = Bt + (size_t)n0 * K;
  int nt = K / 64;
  auto stage = [&](int buf, int k0) {
#pragma unroll
    for (int half = 0; half < 2; half++) {
#pragma unroll
      for (int i = 0; i < 2; i++) {
        int idx = i * 256 + tid;
        GLOAD16(Ab + (size_t)(idx >> 2) * K + k0 + half * 32 + (idx & 3) * 8,
                &Al[buf][half][idx * 8]);
      }
      GLOAD16(Bb + (size_t)(tid >> 2) * K + k0 + half * 32 + (tid & 3) * 8,
              &Bl[buf][half][tid * 8]);
    }
  };
  stage(0, 0);
  asm volatile("s_waitcnt vmcnt(0)" ::: "memory");
  __syncthreads();
  int cur = 0;
  for (int t = 0; t < nt; t++) {
    if (t + 1 < nt) stage(cur ^ 1, (t + 1) * 64);
#pragma unroll
    for (int ks = 0; ks < 2; ks++) {
      bf16x8 af[2], bfr[4];
#pragma unroll
      for (int mi = 0; mi < 2; mi++)
        af[mi] = *(const bf16x8*)&Al[cur][ks][(rowb + mi * 16 + lr) * 32 + lg * 8];
#pragma unroll
      for (int ni = 0; ni < 4; ni++)
        bfr[ni] = *(const bf16x8*)&Bl[cur][ks][(ni * 16 + lr) * 32 + lg * 8];
#pragma unroll
      for (int mi = 0; mi < 2; mi++)
#pragma unroll
        for (int ni = 0; ni < 4; ni++)
          acc[mi][ni] = __builtin_amdgcn_mfma_f32_16x16x32_bf16(
              af[mi], bfr[ni], acc[mi][ni], 0, 0, 0);
    }
    asm volatile("s_waitcnt vmcnt(0)" ::: "memory");
    __syncthreads();
    cur ^= 1;
  }
#pragma unroll
  for (int mi = 0; mi < 2; mi++)
#pragma unroll
    for (int ni = 0; ni < 4; ni++) {
      int n = n0 + ni * 16 + lr;
#pragma unroll
      for (int r = 0; r < 4; r++) {
        int m = m0 + rowb + mi * 16 + lg * 4 + r;
        float v = acc[mi][ni][r];
        int b = m >> 11, ll = m & 2047;
        if (n < 192)
          Qh[((size_t)(b * NH_ + (n >> 4)) * L_ + ll) * F_ + (n & 15)] = (__bf16)v;
        else if (n < 384)
          Kh[((size_t)(b * NH_ + ((n - 192) >> 4)) * L_ + ll) * F_ + ((n - 192) & 15)] = (__bf16)v;
        else
          Vh[((size_t)(b * NH_ + ((n - 384) >> 6)) * L_ + ll) * DH_ + ((n - 384) & 63)] = (__bf16)v;
      }
    }
  // per-32-row-chunk column sums (wave w = chunk w; bf16-rounded values)
#pragma unroll
  for (int ni = 0; ni < 4; ni++) {
    float cs = 0.f;
#pragma unroll
    for (int mi = 0; mi < 2; mi++)
#pragma unroll
      for (int r = 0; r < 4; r++) cs += (float)(__bf16)acc[mi][ni][r];
    cs += __shfl_xor(cs, 16, 64);
    cs += __shfl_xor(cs, 32, 64);
    if (lg == 0) csl[w][ni * 16 + lr] = cs;
  }
  __syncthreads();
  {
    int chs = tid >> 6, colg = tid & 63;
    int n = n0 + colg;
    if (n >= 192) {
      int b = m0 >> 11;
      int ch32 = ((m0 & 2047) >> 5) + chs;
      float v = csl[chs][colg];
      int h, c;
      if (n < 384) { h = (n - 192) >> 4; c = (n - 192) & 15; }
      else         { h = (n - 384) >> 6; c = 16 + ((n - 384) & 63); }
      csum[((size_t)(b * NH_ + h) * NCH + ch32) * 80 + c] = v;
    }
  }
}

// ---------------- output GEMM (BN=64, BK=64), 2-buffer, swizzled ---------
__global__ __launch_bounds__(256)
void gemm_out(const __bf16* __restrict__ A, const __bf16* __restrict__ Bt,
              int M, int N, int K, float* __restrict__ C) {
  __shared__ __align__(16) __bf16 Al[2][2][128 * 32];
  __shared__ __align__(16) __bf16 Bl[2][2][64 * 32];
  int tid = threadIdx.x;
  int flat = blockIdx.x + gridDim.x * blockIdx.y;
  int swz = xcd_swizzle(flat, gridDim.x * gridDim.y);
  int m0 = (swz / gridDim.x) * 128, n0 = (swz % gridDim.x) * 64;
  int w = tid >> 6, l = tid & 63, lr = l & 15, lg = l >> 4;
  int rowb = w * 32;
  f32x4 acc[2][4] = {};
  const __bf16* Ab = A + (size_t)m0 * K;
  const __bf16* Bb = Bt + (size_t)n0 * K;
  int nt = K / 64;
  auto stage = [&](int buf, int k0) {
#pragma unroll
    for (int half = 0; half < 2; half++) {
#pragma unroll
      for (int i = 0; i < 2; i++) {
        int idx = i * 256 + tid;
        GLOAD16(Ab + (size_t)(idx >> 2) * K + k0 + half * 32 + (idx & 3) * 8,
                &Al[buf][half][idx * 8]);
      }
      GLOAD16(Bb + (size_t)(tid >> 2) * K + k0 + half * 32 + (tid & 3) * 8,
              &Bl[buf][half][tid * 8]);
    }
  };
  stage(0, 0);
  asm volatile("s_waitcnt vmcnt(0)" ::: "memory");
  __syncthreads();
  int cur = 0;
  for (int t = 0; t < nt; t++) {
    if (t + 1 < nt) stage(cur ^ 1, (t + 1) * 64);
#pragma unroll
    for (int ks = 0; ks < 2; ks++) {
      bf16x8 af[2], bfr[4];
#pragma unroll
      for (int mi = 0; mi < 2; mi++)
        af[mi] = *(const bf16x8*)&Al[cur][ks][(rowb + mi * 16 + lr) * 32 + lg * 8];
#pragma unroll
      for (int ni = 0; ni < 4; ni++)
        bfr[ni] = *(const bf16x8*)&Bl[cur][ks][(ni * 16 + lr) * 32 + lg * 8];
#pragma unroll
      for (int mi = 0; mi < 2; mi++)
#pragma unroll
        for (int ni = 0; ni < 4; ni++)
          acc[mi][ni] = __builtin_amdgcn_mfma_f32_16x16x32_bf16(
              af[mi], bfr[ni], acc[mi][ni], 0, 0, 0);
    }
    asm volatile("s_waitcnt vmcnt(0)" ::: "memory");
    __syncthreads();
    cur ^= 1;
  }
#pragma unroll
  for (int mi = 0; mi < 2; mi++)
#pragma unroll
    for (int ni = 0; ni < 4; ni++) {
      int n = n0 + ni * 16 + lr;
#pragma unroll
      for (int r = 0; r < 4; r++) {
        int m = m0 + rowb + mi * 16 + lg * 4 + r;
        C[(size_t)m * N + n] = acc[mi][ni][r];
      }
    }
}

// ---------------- apply: prefix base + in-chunk mean scan (bf16 in) ------
__global__ __launch_bounds__(128)
void scan_apply(const __bf16* __restrict__ Kh, const __bf16* __restrict__ Vh,
                const float* __restrict__ csum,
                __bf16* __restrict__ CKh, __bf16* __restrict__ CVf,
                __bf16* __restrict__ Yb) {
  int bh = blockIdx.y, ch = blockIdx.x;
  int b = bh / NH_, h = bh % NH_;
  int c = threadIdx.x;
  if (c >= 80) return;
  float run = 0.f;
  for (int j = 0; j < ch; j++) run += csum[((size_t)bh * NCH + j) * 80 + c];
  if (c < 16) {
    const __bf16* src = Kh + ((size_t)bh * L_ + ch * CH) * F_ + c;
    __bf16* ckp = CKh + ((size_t)bh * L_ + ch * CH) * F_ + c;
    for (int r = 0; r < CH; r++) {
      float val = (float)src[(size_t)r * F_];
      run += val;
      float mean = run * __builtin_amdgcn_rcpf((float)(ch * CH + r + 1));
      ckp[(size_t)r * F_] = (__bf16)(val - mean);
    }
  } else {
    int d = c - 16;
    const __bf16* src = Vh + ((size_t)bh * L_ + ch * CH) * DH_ + d;
    __bf16* cvbase = CVf + (size_t)bh * 128 * 1024;
    __bf16* yp = Yb + ((size_t)(b * L_ + ch * CH)) * DM + h * DH_ + d;
    for (int r = 0; r < CH; r++) {
      float val = (float)src[(size_t)r * DH_];
      run += val;
      int p = ch * CH + r;
      float mean = run * __builtin_amdgcn_rcpf((float)(p + 1));
      cvbase[(size_t)(p >> 4) * 1024 + d * 16 + (p & 15)] = (__bf16)(val - mean);
      yp[(size_t)r * DM] = (__bf16)mean;
    }
  }
}

// ---------------- attention: paired q-tiles, QBLK=32, XCD-swizzled -------
__global__ __launch_bounds__(256)
void attn_mfma(const __bf16* __restrict__ Qh, const __bf16* __restrict__ CKh,
               const __bf16* __restrict__ CVf, __bf16* __restrict__ qkv,
               float* __restrict__ rs2) {
  __shared__ float slab[4][32][65];
  __shared__ float s2slab[4][32];
  int flat = blockIdx.x + 32 * blockIdx.y;
  int swz = xcd_swizzle(flat, 32 * 24);
  int pairi = swz & 31;
  int bh = swz >> 5;
  int tid = threadIdx.x;
  int w = tid >> 6, l = tid & 63;
  int lp = l & 31, hi = l >> 5;
  const __bf16* ckb = CKh + (size_t)bh * L_ * F_;
  const __bf16* cvb = CVf + (size_t)bh * 128 * 1024;

#pragma unroll
  for (int half = 0; half < 2; half++) {
    int ti = half ? (63 - pairi) : pairi;
    int q0 = ti * 32;
    bf16x8 qb = *(const bf16x8*)(Qh + ((size_t)bh * L_ + q0 + lp) * F_ + hi * 8);
    f32x16 pv0 = {}, pv1 = {};
    float s2 = 0.f;

    int pfirst = (w <= ti) ? w : 0;
    bf16x8 ka = *(const bf16x8*)(ckb + (size_t)(pfirst * 32 + lp) * F_ + hi * 8);
    const __bf16* cvp = cvb + (size_t)(2 * pfirst) * 1024 + lp * 16 + hi * 8;
    bf16x8 bv0 = *(const bf16x8*)(cvp);
    bf16x8 bv1 = *(const bf16x8*)(cvp + 512);
    bf16x8 bv2 = *(const bf16x8*)(cvp + 1024);
    bf16x8 bv3 = *(const bf16x8*)(cvp + 1536);

    for (int pt = w; pt <= ti; pt += 4) {
      int ptn = (pt + 4 <= ti) ? pt + 4 : pt;  // clamped prefetch
      bf16x8 ka_n = *(const bf16x8*)(ckb + (size_t)(ptn * 32 + lp) * F_ + hi * 8);
      const __bf16* cvpn = cvb + (size_t)(2 * ptn) * 1024 + lp * 16 + hi * 8;
      bf16x8 bn0 = *(const bf16x8*)(cvpn);
      bf16x8 bn1 = *(const bf16x8*)(cvpn + 512);
      bf16x8 bn2 = *(const bf16x8*)(cvpn + 1024);
      bf16x8 bn3 = *(const bf16x8*)(cvpn + 1536);

      f32x16 s = {};
      s = __builtin_amdgcn_mfma_f32_32x32x16_bf16(ka, qb, s, 0, 0, 0);
      if (pt == ti) {
#pragma unroll
        for (int reg = 0; reg < 16; reg++) {
          int pidx = (reg & 3) + 8 * (reg >> 2) + 4 * hi;
          if (pidx > lp) s[reg] = 0.f;
        }
      }
#pragma unroll
      for (int reg = 0; reg < 16; reg++) s2 = fmaf(s[reg], s[reg], s2);
      pa_u pa0, pa1;
      pack_p(s, pa0, pa1);
      __builtin_amdgcn_s_setprio(1);
      pv0 = __builtin_amdgcn_mfma_f32_32x32x16_bf16(pa0.v, bv0, pv0, 0, 0, 0);
      pv1 = __builtin_amdgcn_mfma_f32_32x32x16_bf16(pa0.v, bv1, pv1, 0, 0, 0);
      pv0 = __builtin_amdgcn_mfma_f32_32x32x16_bf16(pa1.v, bv2, pv0, 0, 0, 0);
      pv1 = __builtin_amdgcn_mfma_f32_32x32x16_bf16(pa1.v, bv3, pv1, 0, 0, 0);
      __builtin_amdgcn_s_setprio(0);
      ka = ka_n; bv0 = bn0; bv1 = bn1; bv2 = bn2; bv3 = bn3;
    }

    s2 += __shfl_xor(s2, 32, 64);
    if (hi == 0) s2slab[w][lp] = s2;
#pragma unroll
    for (int reg = 0; reg < 16; reg++) {
      int ql = (reg & 3) + 8 * (reg >> 2) + 4 * hi;
      slab[w][ql][lp] = pv0[reg];
      slab[w][ql][32 + lp] = pv1[reg];
    }
    __syncthreads();
    if (tid < 32) {
      float v = s2slab[0][tid] + s2slab[1][tid] + s2slab[2][tid] + s2slab[3][tid];
      rs2[(size_t)bh * L_ + q0 + tid] = v * (1.0f / 128.0f);
    }
    {
      int q = tid >> 3, seg = tid & 7;
      bf16x8 o;
#pragma unroll
      for (int j = 0; j < 8; j++) {
        int d = seg * 8 + j;
        float acc = slab[0][q][d] + slab[1][q][d] + slab[2][q][d] + slab[3][q][d];
        o[j] = (__bf16)(acc * 0.125f);
      }
      *(bf16x8*)(qkv + ((size_t)bh * L_ + q0 + q) * DH_ + seg * 8) = o;
    }
    if (half == 0) __syncthreads();  // slab reuse hazard
  }
}

// ---------------- combine (denominator scan fused): Yb += qkv/denom ------
__global__ __launch_bounds__(256)
void combine_kernel(const __bf16* __restrict__ qkv, const float* __restrict__ rs2,
                    __bf16* __restrict__ Yb) {
  int bh = blockIdx.y, lt = blockIdx.x;
  int b = bh / NH_, h = bh % NH_;
  int t = threadIdx.x;
  int l0 = lt * 256;
  __shared__ float part[256];
  __shared__ float dinv[256];
  const float* rs = rs2 + (size_t)bh * L_;
  float vals[8];
  float run = 0.f;
#pragma unroll
  for (int i = 0; i < 8; i++) { run += rs[t * 8 + i]; vals[i] = run; }
  part[t] = run;
  __syncthreads();
  for (int o = 1; o < 256; o <<= 1) {
    float add = (t >= o) ? part[t - o] : 0.f;
    __syncthreads();
    part[t] += add;
    __syncthreads();
  }
  float base = (t > 0) ? part[t - 1] : 0.f;
#pragma unroll
  for (int i = 0; i < 8; i++) {
    int ll = t * 8 + i;
    if (ll >= l0 && ll < l0 + 256)
      dinv[ll - l0] = 1.0f / ((float)(ll + 1) + base + vals[i]);
  }
  __syncthreads();
#pragma unroll
  for (int it = 0; it < 8; it++) {
    int v = it * 256 + t;
    int ll = v >> 3, d8 = v & 7;
    bf16x8 q8 = *(const bf16x8*)(qkv + ((size_t)bh * L_ + l0 + ll) * DH_ + d8 * 8);
    __bf16* yp = Yb + ((size_t)(b * L_ + l0 + ll)) * DM + h * DH_ + d8 * 8;
    bf16x8 y8 = *(const bf16x8*)yp;
    float iv = dinv[ll];
#pragma unroll
    for (int j = 0; j < 8; j++)
      y8[j] = (__bf16)((float)y8[j] + (float)q8[j] * iv);
    *(bf16x8*)yp = y8;
  }
}

extern "C" void kernel_launch(void* const* d_in, const int* in_sizes, int n_in,
                              void* d_out, int out_size, void* d_ws, size_t ws_size,
                              hipStream_t stream) {
  const float* hs = (const float*)d_in[0];
  const float* Wq = (const float*)d_in[1];
  const float* Wk = (const float*)d_in[2];
  const float* Wv = (const float*)d_in[3];
  const float* Wo = (const float*)d_in[4];
  float* out = (float*)d_out;
  char* w = (char*)d_ws;

  __bf16* hsb   = (__bf16*)(w);                      // 6,291,456
  __bf16* WqkvT = (__bf16*)(w + 6291456);            // 1,769,472
  __bf16* WoT   = (__bf16*)(w + 8060928);            // 1,179,648
  __bf16* Kh    = (__bf16*)(w + 9240576);            // 1,572,864
  __bf16* Vh    = (__bf16*)(w + 10813440);           // 6,291,456
  __bf16* qkvb  = (__bf16*)(w + 28114944);           // 6,291,456
  __bf16* Qh    = (__bf16*)(w + 34406400);           // 1,572,864
  __bf16* CKh   = (__bf16*)(w + 35979264);           // 1,572,864
  __bf16* CVfg  = (__bf16*)(w + 37552128);           // 6,291,456
  __bf16* Yb    = (__bf16*)(w + 43843584);           // 6,291,456
  float*  rs2   = (float*)(w + 50135040);            // 98,304
  float*  csum  = (float*)(w + 50331648);            // 491,520

  prep_kernel<<<2976, 256, 0, stream>>>(hs, Wq, Wk, Wv, Wo, hsb, WqkvT, WoT);
  dim3 g1(1152 / 64, (B_ * L_) / 128);
  gemm_proj<<<g1, 256, 0, stream>>>(hsb, WqkvT, DM, Qh, Kh, Vh, csum);
  dim3 gs(NCH, B_ * NH_);
  scan_apply<<<gs, 128, 0, stream>>>(Kh, Vh, csum, CKh, CVfg, Yb);
  dim3 g3(32, 24);
  attn_mfma<<<g3, 256, 0, stream>>>(Qh, CKh, CVfg, qkvb, rs2);
  dim3 g5(8, 24);
  combine_kernel<<<g5, 256, 0, stream>>>(qkvb, rs2, Yb);
  dim3 g6(DM / 64, (B_ * L_) / 128);
  gemm_out<<<g6, 256, 0, stream>>>(Yb, WoT, B_ * L_, DM, DM, out);
}

// Round 20
// 84.987 us; speedup vs baseline: 1.2586x; 1.0470x over previous
//
#include <hip/hip_runtime.h>
#include <hip/hip_bf16.h>
#include <stdint.h>

constexpr int B_ = 2, L_ = 2048, DM = 768, NH_ = 12, F_ = 16, DH_ = 64;
constexpr int CH = 32, NCH = L_ / CH;  // scan chunking (32-row chunks)

typedef __bf16 bf16x8 __attribute__((ext_vector_type(8)));
typedef __bf16 bf16x4 __attribute__((ext_vector_type(4)));
typedef float f32x4 __attribute__((ext_vector_type(4)));
typedef float f32x16 __attribute__((ext_vector_type(16)));
typedef unsigned u32x2 __attribute__((ext_vector_type(2)));

#define GLOAD16(g, l)                                                        \
  __builtin_amdgcn_global_load_lds(                                          \
      (const __attribute__((address_space(1))) void*)(g),                    \
      (__attribute__((address_space(3))) void*)(l), 16, 0, 0)

__device__ __forceinline__ unsigned cvt_pk_bf16(float lo, float hi) {
  unsigned r;
  asm("v_cvt_pk_bf16_f32 %0, %1, %2" : "=v"(r) : "v"(lo), "v"(hi));
  return r;
}

// XCD-aware work remap (T1): hw-consecutive blocks round-robin XCDs; this
// gives each XCD a contiguous chunk of work ids. Requires nwg % 8 == 0.
__device__ __forceinline__ int xcd_swizzle(int flat, int nwg) {
  int cpx = nwg >> 3;
  return (flat & 7) * cpx + (flat >> 3);
}

union pa_u { unsigned u[4]; bf16x8 v; };

__device__ __forceinline__ void pack_p(const f32x16& s, pa_u& pa0, pa_u& pa1) {
  unsigned w0 = cvt_pk_bf16(s[0], s[1]),   w1 = cvt_pk_bf16(s[2], s[3]);
  unsigned w2 = cvt_pk_bf16(s[4], s[5]),   w3 = cvt_pk_bf16(s[6], s[7]);
  unsigned w4 = cvt_pk_bf16(s[8], s[9]),   w5 = cvt_pk_bf16(s[10], s[11]);
  unsigned w6 = cvt_pk_bf16(s[12], s[13]), w7 = cvt_pk_bf16(s[14], s[15]);
  u32x2 r0 = __builtin_amdgcn_permlane32_swap(w0, w2, false, false);
  u32x2 r1 = __builtin_amdgcn_permlane32_swap(w1, w3, false, false);
  u32x2 r2 = __builtin_amdgcn_permlane32_swap(w4, w6, false, false);
  u32x2 r3 = __builtin_amdgcn_permlane32_swap(w5, w7, false, false);
  pa0.u[0] = r0[0]; pa0.u[1] = r1[0]; pa0.u[2] = r0[1]; pa0.u[3] = r1[1];
  pa1.u[0] = r2[0]; pa1.u[1] = r3[0]; pa1.u[2] = r2[1]; pa1.u[3] = r3[1];
}

// ---------------- prep: LDS-tiled weight transposes + hs cast ------------
__global__ __launch_bounds__(256)
void prep_kernel(const float* __restrict__ hs, const float* __restrict__ Wq,
                 const float* __restrict__ Wk, const float* __restrict__ Wv,
                 const float* __restrict__ Wo, __bf16* __restrict__ hsb,
                 __bf16* __restrict__ WqkvT, __bf16* __restrict__ WoT) {
  int bx = blockIdx.x;
  if (bx < 1440) {
    const float* src; __bf16* dst; int C, kt, nt;
    int id = bx;
    if (id < 144)      { src = Wq; dst = WqkvT;             C = 192; kt = id / 6;  nt = id % 6;  }
    else if (id < 288) { id -= 144; src = Wk; dst = WqkvT + (size_t)192 * 768; C = 192; kt = id / 6;  nt = id % 6;  }
    else if (id < 864) { id -= 288; src = Wv; dst = WqkvT + (size_t)384 * 768; C = 768; kt = id / 24; nt = id % 24; }
    else               { id -= 864; src = Wo; dst = WoT;    C = 768; kt = id / 24; nt = id % 24; }
    __shared__ float ld[32][33];
    int tid = threadIdx.x;
    int r = tid >> 3, cg = tid & 7;
    int k0 = kt * 32, n0 = nt * 32;
    float4 v = *(const float4*)(src + (size_t)(k0 + r) * C + n0 + cg * 4);
    ld[r][cg * 4 + 0] = v.x;
    ld[r][cg * 4 + 1] = v.y;
    ld[r][cg * 4 + 2] = v.z;
    ld[r][cg * 4 + 3] = v.w;
    __syncthreads();
    int nl = tid >> 3, kg = tid & 7;
    bf16x4 o;
#pragma unroll
    for (int j = 0; j < 4; j++) o[j] = (__bf16)ld[kg * 4 + j][nl];
    *(bf16x4*)(dst + (size_t)(n0 + nl) * 768 + k0 + kg * 4) = o;
  } else {
    int base = (bx - 1440) * 2048 + threadIdx.x * 8;
    float4 a = *(const float4*)(hs + base);
    float4 b4 = *(const float4*)(hs + base + 4);
    bf16x8 o;
    o[0] = (__bf16)a.x;  o[1] = (__bf16)a.y;  o[2] = (__bf16)a.z;  o[3] = (__bf16)a.w;
    o[4] = (__bf16)b4.x; o[5] = (__bf16)b4.y; o[6] = (__bf16)b4.z; o[7] = (__bf16)b4.w;
    *(bf16x8*)(hsb + base) = o;
  }
}

// ---------------- projection GEMM (BN=64, BK=64), 2-buffer, swizzled -----
__global__ __launch_bounds__(256)
void gemm_proj(const __bf16* __restrict__ A, const __bf16* __restrict__ Bt,
               int K, __bf16* __restrict__ Qh, __bf16* __restrict__ Kh,
               __bf16* __restrict__ Vh, float* __restrict__ csum) {
  __shared__ __align__(16) __bf16 Al[2][2][128 * 32];
  __shared__ __align__(16) __bf16 Bl[2][2][64 * 32];
  __shared__ float csl[4][64];
  int tid = threadIdx.x;
  int flat = blockIdx.x + gridDim.x * blockIdx.y;
  int swz = xcd_swizzle(flat, gridDim.x * gridDim.y);
  int m0 = (swz / gridDim.x) * 128, n0 = (swz % gridDim.x) * 64;
  int w = tid >> 6, l = tid & 63, lr = l & 15, lg = l >> 4;
  int rowb = w * 32;
  f32x4 acc[2][4] = {};
  const __bf16* Ab = A + (size_t)m0 * K;
  const __bf16* Bb = Bt + (size_t)n0 * K;
  int nt = K / 64;
  auto stage = [&](int buf, int k0) {
#pragma unroll
    for (int half = 0; half < 2; half++) {
#pragma unroll
      for (int i = 0; i < 2; i++) {
        int idx = i * 256 + tid;
        GLOAD16(Ab + (size_t)(idx >> 2) * K + k0 + half * 32 + (idx & 3) * 8,
                &Al[buf][half][idx * 8]);
      }
      GLOAD16(Bb + (size_t)(tid >> 2) * K + k0 + half * 32 + (tid & 3) * 8,
              &Bl[buf][half][tid * 8]);
    }
  };
  stage(0, 0);
  asm volatile("s_waitcnt vmcnt(0)" ::: "memory");
  __syncthreads();
  int cur = 0;
  for (int t = 0; t < nt; t++) {
    if (t + 1 < nt) stage(cur ^ 1, (t + 1) * 64);
#pragma unroll
    for (int ks = 0; ks < 2; ks++) {
      bf16x8 af[2], bfr[4];
#pragma unroll
      for (int mi = 0; mi < 2; mi++)
        af[mi] = *(const bf16x8*)&Al[cur][ks][(rowb + mi * 16 + lr) * 32 + lg * 8];
#pragma unroll
      for (int ni = 0; ni < 4; ni++)
        bfr[ni] = *(const bf16x8*)&Bl[cur][ks][(ni * 16 + lr) * 32 + lg * 8];
#pragma unroll
      for (int mi = 0; mi < 2; mi++)
#pragma unroll
        for (int ni = 0; ni < 4; ni++)
          acc[mi][ni] = __builtin_amdgcn_mfma_f32_16x16x32_bf16(
              af[mi], bfr[ni], acc[mi][ni], 0, 0, 0);
    }
    asm volatile("s_waitcnt vmcnt(0)" ::: "memory");
    __syncthreads();
    cur ^= 1;
  }
#pragma unroll
  for (int mi = 0; mi < 2; mi++)
#pragma unroll
    for (int ni = 0; ni < 4; ni++) {
      int n = n0 + ni * 16 + lr;
#pragma unroll
      for (int r = 0; r < 4; r++) {
        int m = m0 + rowb + mi * 16 + lg * 4 + r;
        float v = acc[mi][ni][r];
        int b = m >> 11, ll = m & 2047;
        if (n < 192)
          Qh[((size_t)(b * NH_ + (n >> 4)) * L_ + ll) * F_ + (n & 15)] = (__bf16)v;
        else if (n < 384)
          Kh[((size_t)(b * NH_ + ((n - 192) >> 4)) * L_ + ll) * F_ + ((n - 192) & 15)] = (__bf16)v;
        else
          Vh[((size_t)(b * NH_ + ((n - 384) >> 6)) * L_ + ll) * DH_ + ((n - 384) & 63)] = (__bf16)v;
      }
    }
  // per-32-row-chunk column sums (wave w = chunk w; bf16-rounded values)
#pragma unroll
  for (int ni = 0; ni < 4; ni++) {
    float cs = 0.f;
#pragma unroll
    for (int mi = 0; mi < 2; mi++)
#pragma unroll
      for (int r = 0; r < 4; r++) cs += (float)(__bf16)acc[mi][ni][r];
    cs += __shfl_xor(cs, 16, 64);
    cs += __shfl_xor(cs, 32, 64);
    if (lg == 0) csl[w][ni * 16 + lr] = cs;
  }
  __syncthreads();
  {
    int chs = tid >> 6, colg = tid & 63;
    int n = n0 + colg;
    if (n >= 192) {
      int b = m0 >> 11;
      int ch32 = ((m0 & 2047) >> 5) + chs;
      float v = csl[chs][colg];
      int h, c;
      if (n < 384) { h = (n - 192) >> 4; c = (n - 192) & 15; }
      else         { h = (n - 384) >> 6; c = 16 + ((n - 384) & 63); }
      csum[((size_t)(b * NH_ + h) * NCH + ch32) * 80 + c] = v;
    }
  }
}

// ---------------- output GEMM (BN=64, BK=64), 2-buffer, swizzled ---------
__global__ __launch_bounds__(256)
void gemm_out(const __bf16* __restrict__ A, const __bf16* __restrict__ Bt,
              int M, int N, int K, float* __restrict__ C) {
  __shared__ __align__(16) __bf16 Al[2][2][128 * 32];
  __shared__ __align__(16) __bf16 Bl[2][2][64 * 32];
  int tid = threadIdx.x;
  int flat = blockIdx.x + gridDim.x * blockIdx.y;
  int swz = xcd_swizzle(flat, gridDim.x * gridDim.y);
  int m0 = (swz / gridDim.x) * 128, n0 = (swz % gridDim.x) * 64;
  int w = tid >> 6, l = tid & 63, lr = l & 15, lg = l >> 4;
  int rowb = w * 32;
  f32x4 acc[2][4] = {};
  const __bf16* Ab = A + (size_t)m0 * K;
  const __bf16* Bb = Bt + (size_t)n0 * K;
  int nt = K / 64;
  auto stage = [&](int buf, int k0) {
#pragma unroll
    for (int half = 0; half < 2; half++) {
#pragma unroll
      for (int i = 0; i < 2; i++) {
        int idx = i * 256 + tid;
        GLOAD16(Ab + (size_t)(idx >> 2) * K + k0 + half * 32 + (idx & 3) * 8,
                &Al[buf][half][idx * 8]);
      }
      GLOAD16(Bb + (size_t)(tid >> 2) * K + k0 + half * 32 + (tid & 3) * 8,
              &Bl[buf][half][tid * 8]);
    }
  };
  stage(0, 0);
  asm volatile("s_waitcnt vmcnt(0)" ::: "memory");
  __syncthreads();
  int cur = 0;
  for (int t = 0; t < nt; t++) {
    if (t + 1 < nt) stage(cur ^ 1, (t + 1) * 64);
#pragma unroll
    for (int ks = 0; ks < 2; ks++) {
      bf16x8 af[2], bfr[4];
#pragma unroll
      for (int mi = 0; mi < 2; mi++)
        af[mi] = *(const bf16x8*)&Al[cur][ks][(rowb + mi * 16 + lr) * 32 + lg * 8];
#pragma unroll
      for (int ni = 0; ni < 4; ni++)
        bfr[ni] = *(const bf16x8*)&Bl[cur][ks][(ni * 16 + lr) * 32 + lg * 8];
#pragma unroll
      for (int mi = 0; mi < 2; mi++)
#pragma unroll
        for (int ni = 0; ni < 4; ni++)
          acc[mi][ni] = __builtin_amdgcn_mfma_f32_16x16x32_bf16(
              af[mi], bfr[ni], acc[mi][ni], 0, 0, 0);
    }
    asm volatile("s_waitcnt vmcnt(0)" ::: "memory");
    __syncthreads();
    cur ^= 1;
  }
#pragma unroll
  for (int mi = 0; mi < 2; mi++)
#pragma unroll
    for (int ni = 0; ni < 4; ni++) {
      int n = n0 + ni * 16 + lr;
#pragma unroll
      for (int r = 0; r < 4; r++) {
        int m = m0 + rowb + mi * 16 + lg * 4 + r;
        C[(size_t)m * N + n] = acc[mi][ni][r];
      }
    }
}

// ---------------- apply: prefix base + in-chunk mean scan (bf16 in) ------
__global__ __launch_bounds__(128)
void scan_apply(const __bf16* __restrict__ Kh, const __bf16* __restrict__ Vh,
                const float* __restrict__ csum,
                __bf16* __restrict__ CKh, __bf16* __restrict__ CVf,
                __bf16* __restrict__ Yb) {
  int bh = blockIdx.y, ch = blockIdx.x;
  int b = bh / NH_, h = bh % NH_;
  int c = threadIdx.x;
  if (c >= 80) return;
  float run = 0.f;
  for (int j = 0; j < ch; j++) run += csum[((size_t)bh * NCH + j) * 80 + c];
  if (c < 16) {
    const __bf16* src = Kh + ((size_t)bh * L_ + ch * CH) * F_ + c;
    __bf16* ckp = CKh + ((size_t)bh * L_ + ch * CH) * F_ + c;
    for (int r = 0; r < CH; r++) {
      float val = (float)src[(size_t)r * F_];
      run += val;
      float mean = run * __builtin_amdgcn_rcpf((float)(ch * CH + r + 1));
      ckp[(size_t)r * F_] = (__bf16)(val - mean);
    }
  } else {
    int d = c - 16;
    const __bf16* src = Vh + ((size_t)bh * L_ + ch * CH) * DH_ + d;
    __bf16* cvbase = CVf + (size_t)bh * 128 * 1024;
    __bf16* yp = Yb + ((size_t)(b * L_ + ch * CH)) * DM + h * DH_ + d;
    for (int r = 0; r < CH; r++) {
      float val = (float)src[(size_t)r * DH_];
      run += val;
      int p = ch * CH + r;
      float mean = run * __builtin_amdgcn_rcpf((float)(p + 1));
      cvbase[(size_t)(p >> 4) * 1024 + d * 16 + (p & 15)] = (__bf16)(val - mean);
      yp[(size_t)r * DM] = (__bf16)mean;
    }
  }
}

// ---------------- attention: paired q-tiles, QBLK=32, XCD-swizzled -------
// s2 reduction split into 4 independent accumulators (breaks 16-deep
// serial fmaf chain); __launch_bounds__(256,4) pins <=128 VGPR.
__global__ __launch_bounds__(256, 4)
void attn_mfma(const __bf16* __restrict__ Qh, const __bf16* __restrict__ CKh,
               const __bf16* __restrict__ CVf, __bf16* __restrict__ qkv,
               float* __restrict__ rs2) {
  __shared__ float slab[4][32][65];
  __shared__ float s2slab[4][32];
  int flat = blockIdx.x + 32 * blockIdx.y;
  int swz = xcd_swizzle(flat, 32 * 24);
  int pairi = swz & 31;
  int bh = swz >> 5;
  int tid = threadIdx.x;
  int w = tid >> 6, l = tid & 63;
  int lp = l & 31, hi = l >> 5;
  const __bf16* ckb = CKh + (size_t)bh * L_ * F_;
  const __bf16* cvb = CVf + (size_t)bh * 128 * 1024;

#pragma unroll
  for (int half = 0; half < 2; half++) {
    int ti = half ? (63 - pairi) : pairi;
    int q0 = ti * 32;
    bf16x8 qb = *(const bf16x8*)(Qh + ((size_t)bh * L_ + q0 + lp) * F_ + hi * 8);
    f32x16 pv0 = {}, pv1 = {};
    float s2a = 0.f, s2b = 0.f, s2c = 0.f, s2d = 0.f;

    int pfirst = (w <= ti) ? w : 0;
    bf16x8 ka = *(const bf16x8*)(ckb + (size_t)(pfirst * 32 + lp) * F_ + hi * 8);
    const __bf16* cvp = cvb + (size_t)(2 * pfirst) * 1024 + lp * 16 + hi * 8;
    bf16x8 bv0 = *(const bf16x8*)(cvp);
    bf16x8 bv1 = *(const bf16x8*)(cvp + 512);
    bf16x8 bv2 = *(const bf16x8*)(cvp + 1024);
    bf16x8 bv3 = *(const bf16x8*)(cvp + 1536);

    for (int pt = w; pt <= ti; pt += 4) {
      int ptn = (pt + 4 <= ti) ? pt + 4 : pt;  // clamped prefetch
      bf16x8 ka_n = *(const bf16x8*)(ckb + (size_t)(ptn * 32 + lp) * F_ + hi * 8);
      const __bf16* cvpn = cvb + (size_t)(2 * ptn) * 1024 + lp * 16 + hi * 8;
      bf16x8 bn0 = *(const bf16x8*)(cvpn);
      bf16x8 bn1 = *(const bf16x8*)(cvpn + 512);
      bf16x8 bn2 = *(const bf16x8*)(cvpn + 1024);
      bf16x8 bn3 = *(const bf16x8*)(cvpn + 1536);

      f32x16 s = {};
      s = __builtin_amdgcn_mfma_f32_32x32x16_bf16(ka, qb, s, 0, 0, 0);
      if (pt == ti) {
#pragma unroll
        for (int reg = 0; reg < 16; reg++) {
          int pidx = (reg & 3) + 8 * (reg >> 2) + 4 * hi;
          if (pidx > lp) s[reg] = 0.f;
        }
      }
#pragma unroll
      for (int reg = 0; reg < 4; reg++) {
        s2a = fmaf(s[reg], s[reg], s2a);
        s2b = fmaf(s[4 + reg], s[4 + reg], s2b);
        s2c = fmaf(s[8 + reg], s[8 + reg], s2c);
        s2d = fmaf(s[12 + reg], s[12 + reg], s2d);
      }
      pa_u pa0, pa1;
      pack_p(s, pa0, pa1);
      __builtin_amdgcn_s_setprio(1);
      pv0 = __builtin_amdgcn_mfma_f32_32x32x16_bf16(pa0.v, bv0, pv0, 0, 0, 0);
      pv1 = __builtin_amdgcn_mfma_f32_32x32x16_bf16(pa0.v, bv1, pv1, 0, 0, 0);
      pv0 = __builtin_amdgcn_mfma_f32_32x32x16_bf16(pa1.v, bv2, pv0, 0, 0, 0);
      pv1 = __builtin_amdgcn_mfma_f32_32x32x16_bf16(pa1.v, bv3, pv1, 0, 0, 0);
      __builtin_amdgcn_s_setprio(0);
      ka = ka_n; bv0 = bn0; bv1 = bn1; bv2 = bn2; bv3 = bn3;
    }

    float s2 = (s2a + s2b) + (s2c + s2d);
    s2 += __shfl_xor(s2, 32, 64);
    if (hi == 0) s2slab[w][lp] = s2;
#pragma unroll
    for (int reg = 0; reg < 16; reg++) {
      int ql = (reg & 3) + 8 * (reg >> 2) + 4 * hi;
      slab[w][ql][lp] = pv0[reg];
      slab[w][ql][32 + lp] = pv1[reg];
    }
    __syncthreads();
    if (tid < 32) {
      float v = s2slab[0][tid] + s2slab[1][tid] + s2slab[2][tid] + s2slab[3][tid];
      rs2[(size_t)bh * L_ + q0 + tid] = v * (1.0f / 128.0f);
    }
    {
      int q = tid >> 3, seg = tid & 7;
      bf16x8 o;
#pragma unroll
      for (int j = 0; j < 8; j++) {
        int d = seg * 8 + j;
        float acc = slab[0][q][d] + slab[1][q][d] + slab[2][q][d] + slab[3][q][d];
        o[j] = (__bf16)(acc * 0.125f);
      }
      *(bf16x8*)(qkv + ((size_t)bh * L_ + q0 + q) * DH_ + seg * 8) = o;
    }
    if (half == 0) __syncthreads();  // slab reuse hazard
  }
}

// ---------------- combine (denominator scan fused): Yb += qkv/denom ------
__global__ __launch_bounds__(256)
void combine_kernel(const __bf16* __restrict__ qkv, const float* __restrict__ rs2,
                    __bf16* __restrict__ Yb) {
  int bh = blockIdx.y, lt = blockIdx.x;
  int b = bh / NH_, h = bh % NH_;
  int t = threadIdx.x;
  int l0 = lt * 256;
  __shared__ float part[256];
  __shared__ float dinv[256];
  const float* rs = rs2 + (size_t)bh * L_;
  float vals[8];
  float run = 0.f;
#pragma unroll
  for (int i = 0; i < 8; i++) { run += rs[t * 8 + i]; vals[i] = run; }
  part[t] = run;
  __syncthreads();
  for (int o = 1; o < 256; o <<= 1) {
    float add = (t >= o) ? part[t - o] : 0.f;
    __syncthreads();
    part[t] += add;
    __syncthreads();
  }
  float base = (t > 0) ? part[t - 1] : 0.f;
#pragma unroll
  for (int i = 0; i < 8; i++) {
    int ll = t * 8 + i;
    if (ll >= l0 && ll < l0 + 256)
      dinv[ll - l0] = 1.0f / ((float)(ll + 1) + base + vals[i]);
  }
  __syncthreads();
#pragma unroll
  for (int it = 0; it < 8; it++) {
    int v = it * 256 + t;
    int ll = v >> 3, d8 = v & 7;
    bf16x8 q8 = *(const bf16x8*)(qkv + ((size_t)bh * L_ + l0 + ll) * DH_ + d8 * 8);
    __bf16* yp = Yb + ((size_t)(b * L_ + l0 + ll)) * DM + h * DH_ + d8 * 8;
    bf16x8 y8 = *(const bf16x8*)yp;
    float iv = dinv[ll];
#pragma unroll
    for (int j = 0; j < 8; j++)
      y8[j] = (__bf16)((float)y8[j] + (float)q8[j] * iv);
    *(bf16x8*)yp = y8;
  }
}

extern "C" void kernel_launch(void* const* d_in, const int* in_sizes, int n_in,
                              void* d_out, int out_size, void* d_ws, size_t ws_size,
                              hipStream_t stream) {
  const float* hs = (const float*)d_in[0];
  const float* Wq = (const float*)d_in[1];
  const float* Wk = (const float*)d_in[2];
  const float* Wv = (const float*)d_in[3];
  const float* Wo = (const float*)d_in[4];
  float* out = (float*)d_out;
  char* w = (char*)d_ws;

  __bf16* hsb   = (__bf16*)(w);                      // 6,291,456
  __bf16* WqkvT = (__bf16*)(w + 6291456);            // 1,769,472
  __bf16* WoT   = (__bf16*)(w + 8060928);            // 1,179,648
  __bf16* Kh    = (__bf16*)(w + 9240576);            // 1,572,864
  __bf16* Vh    = (__bf16*)(w + 10813440);           // 6,291,456
  __bf16* qkvb  = (__bf16*)(w + 28114944);           // 6,291,456
  __bf16* Qh    = (__bf16*)(w + 34406400);           // 1,572,864
  __bf16* CKh   = (__bf16*)(w + 35979264);           // 1,572,864
  __bf16* CVfg  = (__bf16*)(w + 37552128);           // 6,291,456
  __bf16* Yb    = (__bf16*)(w + 43843584);           // 6,291,456
  float*  rs2   = (float*)(w + 50135040);            // 98,304
  float*  csum  = (float*)(w + 50331648);            // 491,520

  prep_kernel<<<2976, 256, 0, stream>>>(hs, Wq, Wk, Wv, Wo, hsb, WqkvT, WoT);
  dim3 g1(1152 / 64, (B_ * L_) / 128);
  gemm_proj<<<g1, 256, 0, stream>>>(hsb, WqkvT, DM, Qh, Kh, Vh, csum);
  dim3 gs(NCH, B_ * NH_);
  scan_apply<<<gs, 128, 0, stream>>>(Kh, Vh, csum, CKh, CVfg, Yb);
  dim3 g3(32, 24);
  attn_mfma<<<g3, 256, 0, stream>>>(Qh, CKh, CVfg, qkvb, rs2);
  dim3 g5(8, 24);
  combine_kernel<<<g5, 256, 0, stream>>>(qkvb, rs2, Yb);
  dim3 g6(DM / 64, (B_ * L_) / 128);
  gemm_out<<<g6, 256, 0, stream>>>(Yb, WoT, B_ * L_, DM, DM, out);
}

// Round 21
// 83.290 us; speedup vs baseline: 1.2842x; 1.0204x over previous
//
#include <hip/hip_runtime.h>
#include <hip/hip_bf16.h>
#include <stdint.h>

constexpr int B_ = 2, L_ = 2048, DM = 768, NH_ = 12, F_ = 16, DH_ = 64;
constexpr int CH = 32, NCH = L_ / CH;  // scan chunking (32-row chunks)

typedef __bf16 bf16x8 __attribute__((ext_vector_type(8)));
typedef __bf16 bf16x4 __attribute__((ext_vector_type(4)));
typedef float f32x4 __attribute__((ext_vector_type(4)));
typedef float f32x16 __attribute__((ext_vector_type(16)));
typedef unsigned u32x2 __attribute__((ext_vector_type(2)));

#define GLOAD16(g, l)                                                        \
  __builtin_amdgcn_global_load_lds(                                          \
      (const __attribute__((address_space(1))) void*)(g),                    \
      (__attribute__((address_space(3))) void*)(l), 16, 0, 0)

__device__ __forceinline__ unsigned cvt_pk_bf16(float lo, float hi) {
  unsigned r;
  asm("v_cvt_pk_bf16_f32 %0, %1, %2" : "=v"(r) : "v"(lo), "v"(hi));
  return r;
}

// XCD-aware work remap (T1): hw-consecutive blocks round-robin XCDs; this
// gives each XCD a contiguous chunk of work ids. Requires nwg % 8 == 0.
__device__ __forceinline__ int xcd_swizzle(int flat, int nwg) {
  int cpx = nwg >> 3;
  return (flat & 7) * cpx + (flat >> 3);
}

union pa_u { unsigned u[4]; bf16x8 v; };

__device__ __forceinline__ void pack_p(const f32x16& s, pa_u& pa0, pa_u& pa1) {
  unsigned w0 = cvt_pk_bf16(s[0], s[1]),   w1 = cvt_pk_bf16(s[2], s[3]);
  unsigned w2 = cvt_pk_bf16(s[4], s[5]),   w3 = cvt_pk_bf16(s[6], s[7]);
  unsigned w4 = cvt_pk_bf16(s[8], s[9]),   w5 = cvt_pk_bf16(s[10], s[11]);
  unsigned w6 = cvt_pk_bf16(s[12], s[13]), w7 = cvt_pk_bf16(s[14], s[15]);
  u32x2 r0 = __builtin_amdgcn_permlane32_swap(w0, w2, false, false);
  u32x2 r1 = __builtin_amdgcn_permlane32_swap(w1, w3, false, false);
  u32x2 r2 = __builtin_amdgcn_permlane32_swap(w4, w6, false, false);
  u32x2 r3 = __builtin_amdgcn_permlane32_swap(w5, w7, false, false);
  pa0.u[0] = r0[0]; pa0.u[1] = r1[0]; pa0.u[2] = r0[1]; pa0.u[3] = r1[1];
  pa1.u[0] = r2[0]; pa1.u[1] = r3[0]; pa1.u[2] = r2[1]; pa1.u[3] = r3[1];
}

// ---------------- prep: LDS-tiled weight transposes + hs cast ------------
__global__ __launch_bounds__(256)
void prep_kernel(const float* __restrict__ hs, const float* __restrict__ Wq,
                 const float* __restrict__ Wk, const float* __restrict__ Wv,
                 const float* __restrict__ Wo, __bf16* __restrict__ hsb,
                 __bf16* __restrict__ WqkvT, __bf16* __restrict__ WoT) {
  int bx = blockIdx.x;
  if (bx < 1440) {
    const float* src; __bf16* dst; int C, kt, nt;
    int id = bx;
    if (id < 144)      { src = Wq; dst = WqkvT;             C = 192; kt = id / 6;  nt = id % 6;  }
    else if (id < 288) { id -= 144; src = Wk; dst = WqkvT + (size_t)192 * 768; C = 192; kt = id / 6;  nt = id % 6;  }
    else if (id < 864) { id -= 288; src = Wv; dst = WqkvT + (size_t)384 * 768; C = 768; kt = id / 24; nt = id % 24; }
    else               { id -= 864; src = Wo; dst = WoT;    C = 768; kt = id / 24; nt = id % 24; }
    __shared__ float ld[32][33];
    int tid = threadIdx.x;
    int r = tid >> 3, cg = tid & 7;
    int k0 = kt * 32, n0 = nt * 32;
    float4 v = *(const float4*)(src + (size_t)(k0 + r) * C + n0 + cg * 4);
    ld[r][cg * 4 + 0] = v.x;
    ld[r][cg * 4 + 1] = v.y;
    ld[r][cg * 4 + 2] = v.z;
    ld[r][cg * 4 + 3] = v.w;
    __syncthreads();
    int nl = tid >> 3, kg = tid & 7;
    bf16x4 o;
#pragma unroll
    for (int j = 0; j < 4; j++) o[j] = (__bf16)ld[kg * 4 + j][nl];
    *(bf16x4*)(dst + (size_t)(n0 + nl) * 768 + k0 + kg * 4) = o;
  } else {
    int base = (bx - 1440) * 2048 + threadIdx.x * 8;
    float4 a = *(const float4*)(hs + base);
    float4 b4 = *(const float4*)(hs + base + 4);
    bf16x8 o;
    o[0] = (__bf16)a.x;  o[1] = (__bf16)a.y;  o[2] = (__bf16)a.z;  o[3] = (__bf16)a.w;
    o[4] = (__bf16)b4.x; o[5] = (__bf16)b4.y; o[6] = (__bf16)b4.z; o[7] = (__bf16)b4.w;
    *(bf16x8*)(hsb + base) = o;
  }
}

// ---------------- projection GEMM (BM=64, BN=64, BK=64), swizzled --------
// 64x64 tile, 1152 blocks, 4 waves in 2x2; wave (wr,wc) owns a 32x32 quad.
__global__ __launch_bounds__(256)
void gemm_proj(const __bf16* __restrict__ A, const __bf16* __restrict__ Bt,
               int K, __bf16* __restrict__ Qh, __bf16* __restrict__ Kh,
               __bf16* __restrict__ Vh, float* __restrict__ csum) {
  __shared__ __align__(16) __bf16 Al[2][2][64 * 32];
  __shared__ __align__(16) __bf16 Bl[2][2][64 * 32];
  __shared__ float csl[2][64];
  int tid = threadIdx.x;
  int flat = blockIdx.x + gridDim.x * blockIdx.y;
  int swz = xcd_swizzle(flat, gridDim.x * gridDim.y);
  int m0 = (swz / gridDim.x) * 64, n0 = (swz % gridDim.x) * 64;
  int w = tid >> 6, l = tid & 63, lr = l & 15, lg = l >> 4;
  int wr = w & 1, wc = w >> 1;
  f32x4 acc[2][2] = {};
  const __bf16* Ab = A + (size_t)m0 * K;
  const __bf16* Bb = Bt + (size_t)n0 * K;
  int nt = K / 64;
  auto stage = [&](int buf, int k0) {
#pragma unroll
    for (int half = 0; half < 2; half++) {
      GLOAD16(Ab + (size_t)(tid >> 2) * K + k0 + half * 32 + (tid & 3) * 8,
              &Al[buf][half][tid * 8]);
      GLOAD16(Bb + (size_t)(tid >> 2) * K + k0 + half * 32 + (tid & 3) * 8,
              &Bl[buf][half][tid * 8]);
    }
  };
  stage(0, 0);
  asm volatile("s_waitcnt vmcnt(0)" ::: "memory");
  __syncthreads();
  int cur = 0;
  for (int t = 0; t < nt; t++) {
    if (t + 1 < nt) stage(cur ^ 1, (t + 1) * 64);
#pragma unroll
    for (int ks = 0; ks < 2; ks++) {
      bf16x8 af[2], bfr[2];
#pragma unroll
      for (int mi = 0; mi < 2; mi++)
        af[mi] = *(const bf16x8*)&Al[cur][ks][(wr * 32 + mi * 16 + lr) * 32 + lg * 8];
#pragma unroll
      for (int ni = 0; ni < 2; ni++)
        bfr[ni] = *(const bf16x8*)&Bl[cur][ks][(wc * 32 + ni * 16 + lr) * 32 + lg * 8];
#pragma unroll
      for (int mi = 0; mi < 2; mi++)
#pragma unroll
        for (int ni = 0; ni < 2; ni++)
          acc[mi][ni] = __builtin_amdgcn_mfma_f32_16x16x32_bf16(
              af[mi], bfr[ni], acc[mi][ni], 0, 0, 0);
    }
    asm volatile("s_waitcnt vmcnt(0)" ::: "memory");
    __syncthreads();
    cur ^= 1;
  }
#pragma unroll
  for (int mi = 0; mi < 2; mi++)
#pragma unroll
    for (int ni = 0; ni < 2; ni++) {
      int n = n0 + wc * 32 + ni * 16 + lr;
#pragma unroll
      for (int r = 0; r < 4; r++) {
        int m = m0 + wr * 32 + mi * 16 + lg * 4 + r;
        float v = acc[mi][ni][r];
        int b = m >> 11, ll = m & 2047;
        if (n < 192)
          Qh[((size_t)(b * NH_ + (n >> 4)) * L_ + ll) * F_ + (n & 15)] = (__bf16)v;
        else if (n < 384)
          Kh[((size_t)(b * NH_ + ((n - 192) >> 4)) * L_ + ll) * F_ + ((n - 192) & 15)] = (__bf16)v;
        else
          Vh[((size_t)(b * NH_ + ((n - 384) >> 6)) * L_ + ll) * DH_ + ((n - 384) & 63)] = (__bf16)v;
      }
    }
  // per-32-row-chunk column sums (chunk = wr half; bf16-rounded values)
#pragma unroll
  for (int ni = 0; ni < 2; ni++) {
    float cs = 0.f;
#pragma unroll
    for (int mi = 0; mi < 2; mi++)
#pragma unroll
      for (int r = 0; r < 4; r++) cs += (float)(__bf16)acc[mi][ni][r];
    cs += __shfl_xor(cs, 16, 64);
    cs += __shfl_xor(cs, 32, 64);
    if (lg == 0) csl[wr][wc * 32 + ni * 16 + lr] = cs;
  }
  __syncthreads();
  if (tid < 128) {
    int chs = tid >> 6, colg = tid & 63;
    int n = n0 + colg;
    if (n >= 192) {
      int b = m0 >> 11;
      int ch32 = ((m0 & 2047) >> 5) + chs;
      float v = csl[chs][colg];
      int h, c;
      if (n < 384) { h = (n - 192) >> 4; c = (n - 192) & 15; }
      else         { h = (n - 384) >> 6; c = 16 + ((n - 384) & 63); }
      csum[((size_t)(b * NH_ + h) * NCH + ch32) * 80 + c] = v;
    }
  }
}

// ---------------- output GEMM (BM=64, BN=64, BK=64), swizzled ------------
__global__ __launch_bounds__(256)
void gemm_out(const __bf16* __restrict__ A, const __bf16* __restrict__ Bt,
              int M, int N, int K, float* __restrict__ C) {
  __shared__ __align__(16) __bf16 Al[2][2][64 * 32];
  __shared__ __align__(16) __bf16 Bl[2][2][64 * 32];
  int tid = threadIdx.x;
  int flat = blockIdx.x + gridDim.x * blockIdx.y;
  int swz = xcd_swizzle(flat, gridDim.x * gridDim.y);
  int m0 = (swz / gridDim.x) * 64, n0 = (swz % gridDim.x) * 64;
  int w = tid >> 6, l = tid & 63, lr = l & 15, lg = l >> 4;
  int wr = w & 1, wc = w >> 1;
  f32x4 acc[2][2] = {};
  const __bf16* Ab = A + (size_t)m0 * K;
  const __bf16* Bb = Bt + (size_t)n0 * K;
  int nt = K / 64;
  auto stage = [&](int buf, int k0) {
#pragma unroll
    for (int half = 0; half < 2; half++) {
      GLOAD16(Ab + (size_t)(tid >> 2) * K + k0 + half * 32 + (tid & 3) * 8,
              &Al[buf][half][tid * 8]);
      GLOAD16(Bb + (size_t)(tid >> 2) * K + k0 + half * 32 + (tid & 3) * 8,
              &Bl[buf][half][tid * 8]);
    }
  };
  stage(0, 0);
  asm volatile("s_waitcnt vmcnt(0)" ::: "memory");
  __syncthreads();
  int cur = 0;
  for (int t = 0; t < nt; t++) {
    if (t + 1 < nt) stage(cur ^ 1, (t + 1) * 64);
#pragma unroll
    for (int ks = 0; ks < 2; ks++) {
      bf16x8 af[2], bfr[2];
#pragma unroll
      for (int mi = 0; mi < 2; mi++)
        af[mi] = *(const bf16x8*)&Al[cur][ks][(wr * 32 + mi * 16 + lr) * 32 + lg * 8];
#pragma unroll
      for (int ni = 0; ni < 2; ni++)
        bfr[ni] = *(const bf16x8*)&Bl[cur][ks][(wc * 32 + ni * 16 + lr) * 32 + lg * 8];
#pragma unroll
      for (int mi = 0; mi < 2; mi++)
#pragma unroll
        for (int ni = 0; ni < 2; ni++)
          acc[mi][ni] = __builtin_amdgcn_mfma_f32_16x16x32_bf16(
              af[mi], bfr[ni], acc[mi][ni], 0, 0, 0);
    }
    asm volatile("s_waitcnt vmcnt(0)" ::: "memory");
    __syncthreads();
    cur ^= 1;
  }
#pragma unroll
  for (int mi = 0; mi < 2; mi++)
#pragma unroll
    for (int ni = 0; ni < 2; ni++) {
      int n = n0 + wc * 32 + ni * 16 + lr;
#pragma unroll
      for (int r = 0; r < 4; r++) {
        int m = m0 + wr * 32 + mi * 16 + lg * 4 + r;
        C[(size_t)m * N + n] = acc[mi][ni][r];
      }
    }
}

// ---------------- apply: prefix base + in-chunk mean scan (bf16 in) ------
__global__ __launch_bounds__(128)
void scan_apply(const __bf16* __restrict__ Kh, const __bf16* __restrict__ Vh,
                const float* __restrict__ csum,
                __bf16* __restrict__ CKh, __bf16* __restrict__ CVf,
                __bf16* __restrict__ Yb) {
  int bh = blockIdx.y, ch = blockIdx.x;
  int b = bh / NH_, h = bh % NH_;
  int c = threadIdx.x;
  if (c >= 80) return;
  float run = 0.f;
  for (int j = 0; j < ch; j++) run += csum[((size_t)bh * NCH + j) * 80 + c];
  if (c < 16) {
    const __bf16* src = Kh + ((size_t)bh * L_ + ch * CH) * F_ + c;
    __bf16* ckp = CKh + ((size_t)bh * L_ + ch * CH) * F_ + c;
    for (int r = 0; r < CH; r++) {
      float val = (float)src[(size_t)r * F_];
      run += val;
      float mean = run * __builtin_amdgcn_rcpf((float)(ch * CH + r + 1));
      ckp[(size_t)r * F_] = (__bf16)(val - mean);
    }
  } else {
    int d = c - 16;
    const __bf16* src = Vh + ((size_t)bh * L_ + ch * CH) * DH_ + d;
    __bf16* cvbase = CVf + (size_t)bh * 128 * 1024;
    __bf16* yp = Yb + ((size_t)(b * L_ + ch * CH)) * DM + h * DH_ + d;
    for (int r = 0; r < CH; r++) {
      float val = (float)src[(size_t)r * DH_];
      run += val;
      int p = ch * CH + r;
      float mean = run * __builtin_amdgcn_rcpf((float)(p + 1));
      cvbase[(size_t)(p >> 4) * 1024 + d * 16 + (p & 15)] = (__bf16)(val - mean);
      yp[(size_t)r * DM] = (__bf16)mean;
    }
  }
}

// ---------------- attention: paired q-tiles, QBLK=32, XCD-swizzled -------
__global__ __launch_bounds__(256, 4)
void attn_mfma(const __bf16* __restrict__ Qh, const __bf16* __restrict__ CKh,
               const __bf16* __restrict__ CVf, __bf16* __restrict__ qkv,
               float* __restrict__ rs2) {
  __shared__ float slab[4][32][65];
  __shared__ float s2slab[4][32];
  int flat = blockIdx.x + 32 * blockIdx.y;
  int swz = xcd_swizzle(flat, 32 * 24);
  int pairi = swz & 31;
  int bh = swz >> 5;
  int tid = threadIdx.x;
  int w = tid >> 6, l = tid & 63;
  int lp = l & 31, hi = l >> 5;
  const __bf16* ckb = CKh + (size_t)bh * L_ * F_;
  const __bf16* cvb = CVf + (size_t)bh * 128 * 1024;

#pragma unroll
  for (int half = 0; half < 2; half++) {
    int ti = half ? (63 - pairi) : pairi;
    int q0 = ti * 32;
    bf16x8 qb = *(const bf16x8*)(Qh + ((size_t)bh * L_ + q0 + lp) * F_ + hi * 8);
    f32x16 pv0 = {}, pv1 = {};
    float s2a = 0.f, s2b = 0.f, s2c = 0.f, s2d = 0.f;

    int pfirst = (w <= ti) ? w : 0;
    bf16x8 ka = *(const bf16x8*)(ckb + (size_t)(pfirst * 32 + lp) * F_ + hi * 8);
    const __bf16* cvp = cvb + (size_t)(2 * pfirst) * 1024 + lp * 16 + hi * 8;
    bf16x8 bv0 = *(const bf16x8*)(cvp);
    bf16x8 bv1 = *(const bf16x8*)(cvp + 512);
    bf16x8 bv2 = *(const bf16x8*)(cvp + 1024);
    bf16x8 bv3 = *(const bf16x8*)(cvp + 1536);

    for (int pt = w; pt <= ti; pt += 4) {
      int ptn = (pt + 4 <= ti) ? pt + 4 : pt;  // clamped prefetch
      bf16x8 ka_n = *(const bf16x8*)(ckb + (size_t)(ptn * 32 + lp) * F_ + hi * 8);
      const __bf16* cvpn = cvb + (size_t)(2 * ptn) * 1024 + lp * 16 + hi * 8;
      bf16x8 bn0 = *(const bf16x8*)(cvpn);
      bf16x8 bn1 = *(const bf16x8*)(cvpn + 512);
      bf16x8 bn2 = *(const bf16x8*)(cvpn + 1024);
      bf16x8 bn3 = *(const bf16x8*)(cvpn + 1536);

      f32x16 s = {};
      s = __builtin_amdgcn_mfma_f32_32x32x16_bf16(ka, qb, s, 0, 0, 0);
      if (pt == ti) {
#pragma unroll
        for (int reg = 0; reg < 16; reg++) {
          int pidx = (reg & 3) + 8 * (reg >> 2) + 4 * hi;
          if (pidx > lp) s[reg] = 0.f;
        }
      }
#pragma unroll
      for (int reg = 0; reg < 4; reg++) {
        s2a = fmaf(s[reg], s[reg], s2a);
        s2b = fmaf(s[4 + reg], s[4 + reg], s2b);
        s2c = fmaf(s[8 + reg], s[8 + reg], s2c);
        s2d = fmaf(s[12 + reg], s[12 + reg], s2d);
      }
      pa_u pa0, pa1;
      pack_p(s, pa0, pa1);
      __builtin_amdgcn_s_setprio(1);
      pv0 = __builtin_amdgcn_mfma_f32_32x32x16_bf16(pa0.v, bv0, pv0, 0, 0, 0);
      pv1 = __builtin_amdgcn_mfma_f32_32x32x16_bf16(pa0.v, bv1, pv1, 0, 0, 0);
      pv0 = __builtin_amdgcn_mfma_f32_32x32x16_bf16(pa1.v, bv2, pv0, 0, 0, 0);
      pv1 = __builtin_amdgcn_mfma_f32_32x32x16_bf16(pa1.v, bv3, pv1, 0, 0, 0);
      __builtin_amdgcn_s_setprio(0);
      ka = ka_n; bv0 = bn0; bv1 = bn1; bv2 = bn2; bv3 = bn3;
    }

    float s2 = (s2a + s2b) + (s2c + s2d);
    s2 += __shfl_xor(s2, 32, 64);
    if (hi == 0) s2slab[w][lp] = s2;
#pragma unroll
    for (int reg = 0; reg < 16; reg++) {
      int ql = (reg & 3) + 8 * (reg >> 2) + 4 * hi;
      slab[w][ql][lp] = pv0[reg];
      slab[w][ql][32 + lp] = pv1[reg];
    }
    __syncthreads();
    if (tid < 32) {
      float v = s2slab[0][tid] + s2slab[1][tid] + s2slab[2][tid] + s2slab[3][tid];
      rs2[(size_t)bh * L_ + q0 + tid] = v * (1.0f / 128.0f);
    }
    {
      int q = tid >> 3, seg = tid & 7;
      bf16x8 o;
#pragma unroll
      for (int j = 0; j < 8; j++) {
        int d = seg * 8 + j;
        float acc = slab[0][q][d] + slab[1][q][d] + slab[2][q][d] + slab[3][q][d];
        o[j] = (__bf16)(acc * 0.125f);
      }
      *(bf16x8*)(qkv + ((size_t)bh * L_ + q0 + q) * DH_ + seg * 8) = o;
    }
    if (half == 0) __syncthreads();  // slab reuse hazard
  }
}

// ---------------- combine (denominator scan fused): Yb += qkv/denom ------
__global__ __launch_bounds__(256)
void combine_kernel(const __bf16* __restrict__ qkv, const float* __restrict__ rs2,
                    __bf16* __restrict__ Yb) {
  int bh = blockIdx.y, lt = blockIdx.x;
  int b = bh / NH_, h = bh % NH_;
  int t = threadIdx.x;
  int l0 = lt * 256;
  __shared__ float part[256];
  __shared__ float dinv[256];
  const float* rs = rs2 + (size_t)bh * L_;
  float vals[8];
  float run = 0.f;
#pragma unroll
  for (int i = 0; i < 8; i++) { run += rs[t * 8 + i]; vals[i] = run; }
  part[t] = run;
  __syncthreads();
  for (int o = 1; o < 256; o <<= 1) {
    float add = (t >= o) ? part[t - o] : 0.f;
    __syncthreads();
    part[t] += add;
    __syncthreads();
  }
  float base = (t > 0) ? part[t - 1] : 0.f;
#pragma unroll
  for (int i = 0; i < 8; i++) {
    int ll = t * 8 + i;
    if (ll >= l0 && ll < l0 + 256)
      dinv[ll - l0] = 1.0f / ((float)(ll + 1) + base + vals[i]);
  }
  __syncthreads();
#pragma unroll
  for (int it = 0; it < 8; it++) {
    int v = it * 256 + t;
    int ll = v >> 3, d8 = v & 7;
    bf16x8 q8 = *(const bf16x8*)(qkv + ((size_t)bh * L_ + l0 + ll) * DH_ + d8 * 8);
    __bf16* yp = Yb + ((size_t)(b * L_ + l0 + ll)) * DM + h * DH_ + d8 * 8;
    bf16x8 y8 = *(const bf16x8*)yp;
    float iv = dinv[ll];
#pragma unroll
    for (int j = 0; j < 8; j++)
      y8[j] = (__bf16)((float)y8[j] + (float)q8[j] * iv);
    *(bf16x8*)yp = y8;
  }
}

extern "C" void kernel_launch(void* const* d_in, const int* in_sizes, int n_in,
                              void* d_out, int out_size, void* d_ws, size_t ws_size,
                              hipStream_t stream) {
  const float* hs = (const float*)d_in[0];
  const float* Wq = (const float*)d_in[1];
  const float* Wk = (const float*)d_in[2];
  const float* Wv = (const float*)d_in[3];
  const float* Wo = (const float*)d_in[4];
  float* out = (float*)d_out;
  char* w = (char*)d_ws;

  __bf16* hsb   = (__bf16*)(w);                      // 6,291,456
  __bf16* WqkvT = (__bf16*)(w + 6291456);            // 1,769,472
  __bf16* WoT   = (__bf16*)(w + 8060928);            // 1,179,648
  __bf16* Kh    = (__bf16*)(w + 9240576);            // 1,572,864
  __bf16* Vh    = (__bf16*)(w + 10813440);           // 6,291,456
  __bf16* qkvb  = (__bf16*)(w + 28114944);           // 6,291,456
  __bf16* Qh    = (__bf16*)(w + 34406400);           // 1,572,864
  __bf16* CKh   = (__bf16*)(w + 35979264);           // 1,572,864
  __bf16* CVfg  = (__bf16*)(w + 37552128);           // 6,291,456
  __bf16* Yb    = (__bf16*)(w + 43843584);           // 6,291,456
  float*  rs2   = (float*)(w + 50135040);            // 98,304
  float*  csum  = (float*)(w + 50331648);            // 491,520

  prep_kernel<<<2976, 256, 0, stream>>>(hs, Wq, Wk, Wv, Wo, hsb, WqkvT, WoT);
  dim3 g1(1152 / 64, (B_ * L_) / 64);
  gemm_proj<<<g1, 256, 0, stream>>>(hsb, WqkvT, DM, Qh, Kh, Vh, csum);
  dim3 gs(NCH, B_ * NH_);
  scan_apply<<<gs, 128, 0, stream>>>(Kh, Vh, csum, CKh, CVfg, Yb);
  dim3 g3(32, 24);
  attn_mfma<<<g3, 256, 0, stream>>>(Qh, CKh, CVfg, qkvb, rs2);
  dim3 g5(8, 24);
  combine_kernel<<<g5, 256, 0, stream>>>(qkvb, rs2, Yb);
  dim3 g6(DM / 64, (B_ * L_) / 64);
  gemm_out<<<g6, 256, 0, stream>>>(Yb, WoT, B_ * L_, DM, DM, out);
}